// Round 5
// baseline (315.715 us; speedup 1.0000x reference)
//
#include <hip/hip_runtime.h>

// B=2, N=2048, D=1024, H=16, HS=64.
#define D_MODEL 1024
#define NSEQ    2048
#define NBATCH  2
#define NHEAD   16
#define HSZ     64
#define MROWS   4096   // B*N

typedef short s8v  __attribute__((ext_vector_type(8)));   // 8 x bf16 (bit-pattern shorts)
typedef float f32x4 __attribute__((ext_vector_type(4)));
typedef float f32x16 __attribute__((ext_vector_type(16)));
typedef unsigned long long u64;

#define AS1(p) ((__attribute__((address_space(1))) const void*)(p))
#define AS3(p) ((__attribute__((address_space(3))) void*)(p))

__device__ __forceinline__ float b2f(unsigned short s) {
    union { unsigned u; float f; } z; z.u = (unsigned)s << 16; return z.f;
}
__device__ __forceinline__ unsigned short f2b(float f) {
    union { float f; unsigned u; } z; z.f = f;
    unsigned r = z.u + 0x7fffu + ((z.u >> 16) & 1u);   // RNE
    return (unsigned short)(r >> 16);
}
__device__ __forceinline__ float gelu_f(float x) {
    float u = 0.7978845608028654f * (x + 0.044715f * x * x * x);
    float t = 1.f - 2.f / (1.f + __expf(2.f * u));     // tanh(u), saturating
    return 0.5f * x * (1.f + t);
}
__device__ __forceinline__ unsigned cvt_pk_bf16(float lo, float hi) {
    unsigned r;
    asm("v_cvt_pk_bf16_f32 %0, %1, %2" : "=v"(r) : "v"(lo), "v"(hi));
    return r;
}

// ---------- dtype sniff ----------
__global__ __launch_bounds__(256) void sniff_k(const unsigned short* __restrict__ xr,
                                               int* __restrict__ flag) {
    __shared__ int cnt[4];
    int tid = threadIdx.x, ok = 0;
    for (int i = tid; i < 2048; i += 256) {
        unsigned short u = xr[i];
        int e = (u >> 7) & 0xFF;
        if (u == 0 || (e >= 110 && e <= 135)) ok++;
    }
    #pragma unroll
    for (int off = 32; off; off >>= 1) ok += __shfl_down(ok, off);
    if ((tid & 63) == 0) cnt[tid >> 6] = ok;
    __syncthreads();
    if (tid == 0) {
        int tot = cnt[0] + cnt[1] + cnt[2] + cnt[3];
        *flag = (tot > 1843) ? 1 : 0;
    }
}

// ---------- all 7 small vectors in one launch ----------
__global__ __launch_bounds__(256) void cvt_small_k(
    const void* p0, const void* p1, const void* p2, const void* p3,
    const void* p4, const void* p5, const void* p6,
    unsigned short* __restrict__ out, const int* __restrict__ flag)
{
    int i = blockIdx.x * 256 + threadIdx.x;   // 0..8191
    const void* src; int off;
    if      (i < 1024) { src = p0; off = i; }
    else if (i < 2048) { src = p1; off = i - 1024; }
    else if (i < 3072) { src = p2; off = i - 2048; }
    else if (i < 4096) { src = p3; off = i - 3072; }
    else if (i < 5120) { src = p4; off = i - 4096; }
    else if (i < 7168) { src = p5; off = i - 5120; }
    else               { src = p6; off = i - 7168; }
    out[i] = (*flag) ? ((const unsigned short*)src)[off]
                     : f2b(((const float*)src)[off]);
}

// ---------- all 4 weight transposes in one launch ----------
__global__ __launch_bounds__(256) void transpose_all_k(
    const void* wqkv, const void* wout, const void* w1, const void* w2,
    unsigned short* t_qkv, unsigned short* t_out,
    unsigned short* t_w1, unsigned short* t_w2, const int* __restrict__ flag)
{
    __shared__ unsigned short t[32][33];
    int bid = blockIdx.x;
    const void* W; unsigned short* Wt; int K, N, bx, by;
    if      (bid < 3072) { W = wqkv; Wt = t_qkv; K = 1024; N = 3072; bx = bid % 96; by = bid / 96; }
    else if (bid < 4096) { bid -= 3072; W = wout; Wt = t_out; K = 1024; N = 1024; bx = bid % 32; by = bid / 32; }
    else if (bid < 6144) { bid -= 4096; W = w1;   Wt = t_w1;  K = 1024; N = 2048; bx = bid % 64; by = bid / 64; }
    else                 { bid -= 6144; W = w2;   Wt = t_w2;  K = 2048; N = 1024; bx = bid % 32; by = bid / 32; }
    int f = *flag;
    int n0 = bx * 32, k0 = by * 32;
    int x = threadIdx.x & 31, y = threadIdx.x >> 5;   // (32,8) flat
    #pragma unroll
    for (int r = 0; r < 32; r += 8) {
        size_t idx = (size_t)(k0 + r + y) * N + n0 + x;
        t[r + y][x] = f ? ((const unsigned short*)W)[idx]
                        : f2b(((const float*)W)[idx]);
    }
    __syncthreads();
    #pragma unroll
    for (int r = 0; r < 32; r += 8)
        Wt[(size_t)(n0 + r + y) * K + k0 + x] = t[x][r + y];
}

// ---------- LN1 fused with x canonicalization ----------
__global__ __launch_bounds__(256) void ln1f_k(
    const void* __restrict__ x_raw, const unsigned short* __restrict__ scale,
    const unsigned short* __restrict__ bias, unsigned short* __restrict__ xb,
    unsigned short* __restrict__ xn, const int* __restrict__ flag)
{
    int row = blockIdx.x, tid = threadIdx.x;
    int f = *flag;
    float v[4], s = 0.f, s2 = 0.f;
    #pragma unroll
    for (int i = 0; i < 4; ++i) {
        size_t idx = (size_t)row * D_MODEL + tid + i * 256;
        float t = f ? b2f(((const unsigned short*)x_raw)[idx])
                    : ((const float*)x_raw)[idx];
        v[i] = t; s += t; s2 += t * t;
    }
    #pragma unroll
    for (int off = 32; off; off >>= 1) { s += __shfl_down(s, off); s2 += __shfl_down(s2, off); }
    __shared__ float rs[4], rs2[4];
    int w = tid >> 6;
    if ((tid & 63) == 0) { rs[w] = s; rs2[w] = s2; }
    __syncthreads();
    float S  = rs[0] + rs[1] + rs[2] + rs[3];
    float S2 = rs2[0] + rs2[1] + rs2[2] + rs2[3];
    float mean = S * (1.f / D_MODEL);
    float var  = S2 * (1.f / D_MODEL) - mean * mean;
    float rstd = rsqrtf(var + 1e-6f);
    #pragma unroll
    for (int i = 0; i < 4; ++i) {
        int d = tid + i * 256;
        size_t idx = (size_t)row * D_MODEL + d;
        xb[idx] = f2b(v[i]);
        xn[idx] = f2b((v[i] - mean) * rstd * b2f(scale[d]) + b2f(bias[d]));
    }
}

// ---------- LayerNorm (bf16 in) ----------
__global__ __launch_bounds__(256) void ln_k(
    const unsigned short* __restrict__ x, const unsigned short* __restrict__ scale,
    const unsigned short* __restrict__ bias, unsigned short* __restrict__ out)
{
    int row = blockIdx.x, tid = threadIdx.x;
    const unsigned short* xr = x + (size_t)row * D_MODEL;
    float v[4], s = 0.f, s2 = 0.f;
    #pragma unroll
    for (int i = 0; i < 4; ++i) {
        float t = b2f(xr[tid + i * 256]);
        v[i] = t; s += t; s2 += t * t;
    }
    #pragma unroll
    for (int off = 32; off; off >>= 1) { s += __shfl_down(s, off); s2 += __shfl_down(s2, off); }
    __shared__ float rs[4], rs2[4];
    int w = tid >> 6;
    if ((tid & 63) == 0) { rs[w] = s; rs2[w] = s2; }
    __syncthreads();
    float S  = rs[0] + rs[1] + rs[2] + rs[3];
    float S2 = rs2[0] + rs2[1] + rs2[2] + rs2[3];
    float mean = S * (1.f / D_MODEL);
    float var  = S2 * (1.f / D_MODEL) - mean * mean;
    float rstd = rsqrtf(var + 1e-6f);
    #pragma unroll
    for (int i = 0; i < 4; ++i) {
        int d = tid + i * 256;
        out[(size_t)row * D_MODEL + d] =
            f2b((v[i] - mean) * rstd * b2f(scale[d]) + b2f(bias[d]));
    }
}

// ---------- GEMM: 128xTN tile, BK=64, global_load_lds, XOR swizzle ----------
template<int TN, int ACT, int RES, int ODYN>
__global__ __launch_bounds__(256) void gemm128_k(
    const unsigned short* __restrict__ A, const unsigned short* __restrict__ Bt,
    const unsigned short* __restrict__ bias, const unsigned short* __restrict__ resid,
    void* __restrict__ Cp, int M, int Nn, int K, const int* __restrict__ flag)
{
    constexpr int MT = (TN == 128) ? 4 : 2;
    __shared__ short As[128 * 64];
    __shared__ short Bs[TN * 64];
    int tid = threadIdx.x;
    int m0 = blockIdx.y * 128, n0 = blockIdx.x * TN;
    int lane = tid & 63, w = tid >> 6;
    int a_base = (TN == 128) ? (w >> 1) * 64 : w * 32;
    int b_base = (TN == 128) ? (w & 1) * 64 : 0;
    int mm = lane & 15, q = lane >> 4;

    f32x4 zero = {0.f, 0.f, 0.f, 0.f};
    f32x4 acc[MT][4];
    #pragma unroll
    for (int mt = 0; mt < MT; ++mt)
        #pragma unroll
        for (int nt = 0; nt < 4; ++nt) acc[mt][nt] = zero;

    int grow   = lane >> 3;
    int gchunk = ((lane & 7) ^ grow) * 8;
    const unsigned short* Ab = A  + (size_t)(m0 + w * 32 + grow) * K + gchunk;
    const unsigned short* Bb = Bt + (size_t)(n0 + w * (TN / 4) + grow) * K + gchunk;
    int swz = (mm & 7);

    for (int k0 = 0; k0 < K; k0 += 64) {
        __syncthreads();
        #pragma unroll
        for (int s = 0; s < 4; ++s)
            __builtin_amdgcn_global_load_lds(AS1(Ab + k0 + (size_t)(s * 8) * K),
                                             AS3(&As[(w * 32 + s * 8) * 64]), 16, 0, 0);
        #pragma unroll
        for (int s = 0; s < TN / 32; ++s)
            __builtin_amdgcn_global_load_lds(AS1(Bb + k0 + (size_t)(s * 8) * K),
                                             AS3(&Bs[(w * (TN / 4) + s * 8) * 64]), 16, 0, 0);
        __syncthreads();
        #pragma unroll
        for (int kk = 0; kk < 2; ++kk) {
            int col = ((kk * 4 + q) ^ swz) * 8;
            s8v af[MT], bf[4];
            #pragma unroll
            for (int mt = 0; mt < MT; ++mt)
                af[mt] = *(const s8v*)&As[(a_base + mt * 16 + mm) * 64 + col];
            #pragma unroll
            for (int nt = 0; nt < 4; ++nt)
                bf[nt] = *(const s8v*)&Bs[(b_base + nt * 16 + mm) * 64 + col];
            #pragma unroll
            for (int mt = 0; mt < MT; ++mt)
                #pragma unroll
                for (int nt = 0; nt < 4; ++nt)
                    acc[mt][nt] = __builtin_amdgcn_mfma_f32_16x16x32_bf16(
                        af[mt], bf[nt], acc[mt][nt], 0, 0, 0);
        }
    }

    int f = ODYN ? *flag : 1;
    #pragma unroll
    for (int nt = 0; nt < 4; ++nt) {
        int gc = n0 + b_base + nt * 16 + mm;
        float bv = bias ? b2f(bias[gc]) : 0.f;
        #pragma unroll
        for (int mt = 0; mt < MT; ++mt) {
            #pragma unroll
            for (int r = 0; r < 4; ++r) {
                int gr = m0 + a_base + mt * 16 + q * 4 + r;
                float v = acc[mt][nt][r] + bv;
                if (ACT == 1) v = gelu_f(v);
                if (RES == 1) v += b2f(resid[(size_t)gr * Nn + gc]);
                if (f) ((unsigned short*)Cp)[(size_t)gr * Nn + gc] = f2b(v);
                else   ((float*)Cp)[(size_t)gr * Nn + gc] = v;
            }
        }
    }
}

// ---------- flash attention v7: single-wave blocks, zero barriers ----------
// Grid = 32 bh x 64 q-tiles = 2048 blocks of ONE wave (32 queries each).
// 32-key stages; K double-buffered via global_load_lds (pre-swizzled source,
// linear LDS dest); V transpose-packed into a SINGLE 4KB buffer (2 dims per
// 128B row, XOR granule swizzle, sigma-permuted key order so PV's B-frag is
// one ds_read_b128). Same-wave program order replaces all __syncthreads;
// one s_waitcnt vmcnt(0) + sched_barrier per stage covers the gll -> ds_read
// dependency. Swapped QK^T (mfma(K,Q)) keeps softmax lane-local and P in
// registers. Scores s = q.k/8 with LN'd inputs: exp overflow-safe (no-max).
__global__ __launch_bounds__(64) void fattn_k(
    const unsigned short* __restrict__ qkv, unsigned short* __restrict__ attn_out)
{
    int bh = blockIdx.x;
    int h = bh & (NHEAD - 1), b = bh >> 4;
    int qt = (int)gridDim.y - 1 - (int)blockIdx.y;   // heaviest first
    int q0 = qt * 32;
    size_t base = (size_t)b * NSEQ * (3 * D_MODEL);

    __shared__ __align__(16) short Ks[2][2048];   // [32 keys][64 dims], granule-swizzled
    __shared__ __align__(16) short Vt[2048];      // [32 rows][2dims x 32 keys], sigma-packed

    int lane = threadIdx.x;
    int ql = lane & 31, hi = lane >> 5;
    int gq = q0 + ql;

    // Q B-fragments, pre-scaled by 1/8 (exact bf16 exponent decrement)
    s8v qB[4];
    {
        const unsigned short* qrow = qkv + base + (size_t)gq * (3 * D_MODEL) + h * HSZ;
        #pragma unroll
        for (int dc = 0; dc < 4; ++dc) {
            s8v v = *(const s8v*)(qrow + dc * 16 + hi * 8);
            #pragma unroll
            for (int e = 0; e < 8; ++e) {
                unsigned short u = (unsigned short)v[e];
                if (u & 0x7f80u) u = (unsigned short)(u - 0x0180u);
                v[e] = (short)u;
            }
            qB[dc] = v;
        }
    }

    const unsigned short* kbase = qkv + base + D_MODEL + h * HSZ;
    const unsigned short* vbase = qkv + base + 2 * D_MODEL + h * HSZ;

    int r8 = lane >> 3, a7 = lane & 7;
    int ksrc = ((a7 ^ r8) & 7) * 8;          // K src granule pre-swizzle (shorts)
    int vd0 = a7 * 8;                        // V dim base (this lane stages dims vd0..vd0+7)
    int gbase = 2 * (r8 >> 2) + (r8 & 1);    // sigma granule base of this lane's 4-key run
    int sbase = ((r8 >> 1) & 1) * 4;         // in-granule u64 slot (shorts)
    int kswz = (ql & 7);                     // compute-side K XOR
    int vr0 = ql >> 1, vsel = 4 * (ql & 1);  // PV read row/parity (accA); accB adds 16 rows

    f32x16 z16;
    #pragma unroll
    for (int i = 0; i < 16; ++i) z16[i] = 0.f;
    f32x16 accA = z16, accB = z16;           // O dims 0..31 / 32..63
    float l_acc = 0.f;

    s8v va, vb, vc, vd_;

    // ---- prologue: stage 0 ----
    #pragma unroll
    for (int i = 0; i < 4; ++i)
        __builtin_amdgcn_global_load_lds(
            AS1(kbase + (size_t)(i * 8 + r8) * (3 * D_MODEL) + ksrc),
            AS3(&Ks[0][i * 512]), 16, 0, 0);
    {
        const unsigned short* vr_ = vbase + (size_t)(4 * r8) * (3 * D_MODEL) + vd0;
        va  = *(const s8v*)vr_;
        vb  = *(const s8v*)(vr_ + 3 * D_MODEL);
        vc  = *(const s8v*)(vr_ + 6 * D_MODEL);
        vd_ = *(const s8v*)(vr_ + 9 * D_MODEL);
    }
    #pragma unroll
    for (int e = 0; e < 8; ++e) {            // sigma-pack V stage 0
        unsigned plo = (unsigned)(unsigned short)va[e] | ((unsigned)(unsigned short)vb[e] << 16);
        unsigned phi = (unsigned)(unsigned short)vc[e] | ((unsigned)(unsigned short)vd_[e] << 16);
        int vrow = 4 * a7 + (e >> 1);
        int gam = (4 * (e & 1) + gbase) ^ (vrow & 7);
        *(u64*)&Vt[vrow * 64 + gam * 8 + sbase] = (u64)plo | ((u64)phi << 32);
    }
    asm volatile("s_waitcnt vmcnt(0)");
    __builtin_amdgcn_sched_barrier(0);

    int cur = 0;
    for (int s = 0; s <= qt; ++s) {
        bool pre = (s < qt);
        if (pre) {                            // issue stage s+1: K glls + V reg loads
            int jn = 32 * (s + 1);
            #pragma unroll
            for (int i = 0; i < 4; ++i)
                __builtin_amdgcn_global_load_lds(
                    AS1(kbase + (size_t)(jn + i * 8 + r8) * (3 * D_MODEL) + ksrc),
                    AS3(&Ks[cur ^ 1][i * 512]), 16, 0, 0);
            const unsigned short* vr_ = vbase + (size_t)(jn + 4 * r8) * (3 * D_MODEL) + vd0;
            va  = *(const s8v*)vr_;
            vb  = *(const s8v*)(vr_ + 3 * D_MODEL);
            vc  = *(const s8v*)(vr_ + 6 * D_MODEL);
            vd_ = *(const s8v*)(vr_ + 9 * D_MODEL);
        }
        __builtin_amdgcn_sched_barrier(0);    // keep load issue ahead of compute

        // S^T tile: rows = keys, cols = queries
        f32x16 sc = z16;
        __builtin_amdgcn_s_setprio(1);
        #pragma unroll
        for (int dc = 0; dc < 4; ++dc) {
            s8v kf = *(const s8v*)&Ks[cur][ql * 64 + (((2 * dc + hi) ^ kswz) << 3)];
            sc = __builtin_amdgcn_mfma_f32_32x32x16_bf16(kf, qB[dc], sc, 0, 0, 0);
        }
        __builtin_amdgcn_s_setprio(0);

        // lane-local softmax (no max): p = exp(s), causal mask on diagonal stage
        bool needmask = (s == qt);
        #pragma unroll
        for (int r = 0; r < 16; ++r) {
            float p = __expf(sc[r]);
            if (needmask) {
                int gk = 32 * s + (r & 3) + 8 * (r >> 2) + 4 * hi;
                if (gk > gq) p = 0.f;
            }
            l_acc += p;
            sc[r] = p;
        }

        // PV: A-frag in-lane; B-frag = one b128 per (half, dt) in sigma order
        #pragma unroll
        for (int half = 0; half < 2; ++half) {
            union { unsigned u[4]; s8v v; } pu;
            pu.u[0] = cvt_pk_bf16(sc[half * 8 + 0], sc[half * 8 + 1]);
            pu.u[1] = cvt_pk_bf16(sc[half * 8 + 2], sc[half * 8 + 3]);
            pu.u[2] = cvt_pk_bf16(sc[half * 8 + 4], sc[half * 8 + 5]);
            pu.u[3] = cvt_pk_bf16(sc[half * 8 + 6], sc[half * 8 + 7]);
            int gA = (vsel + 2 * half + hi) ^ (vr0 & 7);
            int gB = (vsel + 2 * half + hi) ^ (vr0 & 7);   // rows 16+vr0: (16+x)&7 == x&7
            __builtin_amdgcn_s_setprio(1);
            {
                s8v vv = *(const s8v*)&Vt[vr0 * 64 + (gA << 3)];
                accA = __builtin_amdgcn_mfma_f32_32x32x16_bf16(pu.v, vv, accA, 0, 0, 0);
            }
            {
                s8v vv = *(const s8v*)&Vt[(16 + vr0) * 64 + (gB << 3)];
                accB = __builtin_amdgcn_mfma_f32_32x32x16_bf16(pu.v, vv, accB, 0, 0, 0);
            }
            __builtin_amdgcn_s_setprio(0);
        }

        if (pre) {                            // sigma-pack V(s+1) AFTER PV(s) reads
            #pragma unroll
            for (int e = 0; e < 8; ++e) {
                unsigned plo = (unsigned)(unsigned short)va[e] | ((unsigned)(unsigned short)vb[e] << 16);
                unsigned phi = (unsigned)(unsigned short)vc[e] | ((unsigned)(unsigned short)vd_[e] << 16);
                int vrow = 4 * a7 + (e >> 1);
                int gam = (4 * (e & 1) + gbase) ^ (vrow & 7);
                *(u64*)&Vt[vrow * 64 + gam * 8 + sbase] = (u64)plo | ((u64)phi << 32);
            }
        }
        asm volatile("s_waitcnt vmcnt(0)");   // gll(s+1) landed
        __builtin_amdgcn_sched_barrier(0);
        cur ^= 1;
    }

    // epilogue: combine l across key-halves, normalize, write O
    l_acc += __shfl_xor(l_acc, 32);
    float linv = 1.f / l_acc;
    unsigned short* orow = attn_out + (size_t)b * NSEQ * D_MODEL + h * HSZ;
    #pragma unroll
    for (int r = 0; r < 16; ++r) {
        int cr = (r & 3) + 8 * (r >> 2) + 4 * hi;   // query row within wave
        float ri = __shfl(linv, cr);
        size_t ro = (size_t)(q0 + cr) * D_MODEL;
        orow[ro + ql]      = f2b(accA[r] * ri);
        orow[ro + 32 + ql] = f2b(accB[r] * ri);
    }
}

// ---------- launch ----------
extern "C" void kernel_launch(void* const* d_in, const int* in_sizes, int n_in,
                              void* d_out, int out_size, void* d_ws, size_t ws_size,
                              hipStream_t stream)
{
    const void* x_raw  = d_in[0];
    const void* ln1s_r = d_in[1];
    const void* ln1b_r = d_in[2];
    const void* wqkv_r = d_in[3];
    const void* wout_r = d_in[4];
    const void* bout_r = d_in[5];
    const void* ln2s_r = d_in[6];
    const void* ln2b_r = d_in[7];
    const void* w1_r   = d_in[8];
    const void* b1_r   = d_in[9];
    const void* w2_r   = d_in[10];
    const void* b2_r   = d_in[11];

    char* ws = (char*)d_ws;
    const size_t MB = 1024 * 1024;
    unsigned short* wt_qkv = (unsigned short*)(ws + 0 * MB);
    unsigned short* wt_out = (unsigned short*)(ws + 6 * MB);
    unsigned short* wt_w1  = (unsigned short*)(ws + 8 * MB);
    unsigned short* wt_w2  = (unsigned short*)(ws + 12 * MB);
    unsigned short* xb     = (unsigned short*)(ws + 16 * MB);
    unsigned short* xn     = (unsigned short*)(ws + 24 * MB);
    unsigned short* qkvb   = (unsigned short*)(ws + 32 * MB);
    unsigned short* x1     = (unsigned short*)(ws + 48 * MB);
    int*            flag   = (int*)           (ws + 56 * MB);
    unsigned short* cbias  = (unsigned short*)(ws + 56 * MB + 1024);
    unsigned short* attnb  = xn;
    unsigned short* xn2    = xn;
    unsigned short* hb     = qkvb;

    unsigned short* c_ln1s = cbias + 0;
    unsigned short* c_ln1b = cbias + 1024;
    unsigned short* c_bout = cbias + 2048;
    unsigned short* c_ln2s = cbias + 3072;
    unsigned short* c_ln2b = cbias + 4096;
    unsigned short* c_b1   = cbias + 5120;
    unsigned short* c_b2   = cbias + 7168;

    sniff_k<<<1, 256, 0, stream>>>((const unsigned short*)x_raw, flag);
    cvt_small_k<<<32, 256, 0, stream>>>(ln1s_r, ln1b_r, bout_r, ln2s_r, ln2b_r,
                                        b1_r, b2_r, cbias, flag);
    transpose_all_k<<<8192, 256, 0, stream>>>(wqkv_r, wout_r, w1_r, w2_r,
                                              wt_qkv, wt_out, wt_w1, wt_w2, flag);
    ln1f_k<<<MROWS, 256, 0, stream>>>(x_raw, c_ln1s, c_ln1b, xb, xn, flag);
    gemm128_k<128, 0, 0, 0><<<dim3(24, 32), 256, 0, stream>>>(
        xn, wt_qkv, nullptr, nullptr, qkvb, MROWS, 3072, 1024, flag);
    fattn_k<<<dim3(NBATCH * NHEAD, NSEQ / 32), 64, 0, stream>>>(qkvb, attnb);
    gemm128_k<64, 0, 1, 0><<<dim3(16, 32), 256, 0, stream>>>(
        attnb, wt_out, c_bout, xb, x1, MROWS, 1024, 1024, flag);
    ln_k<<<MROWS, 256, 0, stream>>>(x1, c_ln2s, c_ln2b, xn2);
    gemm128_k<128, 1, 0, 0><<<dim3(16, 32), 256, 0, stream>>>(
        xn2, wt_w1, c_b1, nullptr, hb, MROWS, 2048, 1024, flag);
    gemm128_k<64, 0, 1, 1><<<dim3(16, 32), 256, 0, stream>>>(
        hb, wt_w2, c_b2, x1, d_out, MROWS, 1024, 2048, flag);
}

// Round 6
// 302.707 us; speedup vs baseline: 1.0430x; 1.0430x over previous
//
#include <hip/hip_runtime.h>

// B=2, N=2048, D=1024, H=16, HS=64.
#define D_MODEL 1024
#define NSEQ    2048
#define NBATCH  2
#define NHEAD   16
#define HSZ     64
#define MROWS   4096   // B*N

typedef short s8v  __attribute__((ext_vector_type(8)));   // 8 x bf16 (bit-pattern shorts)
typedef float f32x4 __attribute__((ext_vector_type(4)));

#define AS1(p) ((__attribute__((address_space(1))) const void*)(p))
#define AS3(p) ((__attribute__((address_space(3))) void*)(p))

__device__ __forceinline__ float b2f(unsigned short s) {
    union { unsigned u; float f; } z; z.u = (unsigned)s << 16; return z.f;
}
__device__ __forceinline__ unsigned short f2b(float f) {
    union { float f; unsigned u; } z; z.f = f;
    unsigned r = z.u + 0x7fffu + ((z.u >> 16) & 1u);   // RNE
    return (unsigned short)(r >> 16);
}
__device__ __forceinline__ unsigned short f2b_trunc(float f) {
    union { float f; unsigned u; } z; z.f = f;
    return (unsigned short)(z.u >> 16);
}
__device__ __forceinline__ float gelu_f(float x) {
    float u = 0.7978845608028654f * (x + 0.044715f * x * x * x);
    float t = 1.f - 2.f / (1.f + __expf(2.f * u));     // tanh(u), saturating
    return 0.5f * x * (1.f + t);
}

// ---------- dtype sniff ----------
__global__ __launch_bounds__(256) void sniff_k(const unsigned short* __restrict__ xr,
                                               int* __restrict__ flag) {
    __shared__ int cnt[4];
    int tid = threadIdx.x, ok = 0;
    for (int i = tid; i < 2048; i += 256) {
        unsigned short u = xr[i];
        int e = (u >> 7) & 0xFF;
        if (u == 0 || (e >= 110 && e <= 135)) ok++;
    }
    #pragma unroll
    for (int off = 32; off; off >>= 1) ok += __shfl_down(ok, off);
    if ((tid & 63) == 0) cnt[tid >> 6] = ok;
    __syncthreads();
    if (tid == 0) {
        int tot = cnt[0] + cnt[1] + cnt[2] + cnt[3];
        *flag = (tot > 1843) ? 1 : 0;
    }
}

// ---------- all 7 small vectors in one launch ----------
__global__ __launch_bounds__(256) void cvt_small_k(
    const void* p0, const void* p1, const void* p2, const void* p3,
    const void* p4, const void* p5, const void* p6,
    unsigned short* __restrict__ out, const int* __restrict__ flag)
{
    int i = blockIdx.x * 256 + threadIdx.x;   // 0..8191
    const void* src; int off;
    if      (i < 1024) { src = p0; off = i; }
    else if (i < 2048) { src = p1; off = i - 1024; }
    else if (i < 3072) { src = p2; off = i - 2048; }
    else if (i < 4096) { src = p3; off = i - 3072; }
    else if (i < 5120) { src = p4; off = i - 4096; }
    else if (i < 7168) { src = p5; off = i - 5120; }
    else               { src = p6; off = i - 7168; }
    out[i] = (*flag) ? ((const unsigned short*)src)[off]
                     : f2b(((const float*)src)[off]);
}

// ---------- all 4 weight transposes in one launch ----------
__global__ __launch_bounds__(256) void transpose_all_k(
    const void* wqkv, const void* wout, const void* w1, const void* w2,
    unsigned short* t_qkv, unsigned short* t_out,
    unsigned short* t_w1, unsigned short* t_w2, const int* __restrict__ flag)
{
    __shared__ unsigned short t[32][33];
    int bid = blockIdx.x;
    const void* W; unsigned short* Wt; int K, N, bx, by;
    if      (bid < 3072) { W = wqkv; Wt = t_qkv; K = 1024; N = 3072; bx = bid % 96; by = bid / 96; }
    else if (bid < 4096) { bid -= 3072; W = wout; Wt = t_out; K = 1024; N = 1024; bx = bid % 32; by = bid / 32; }
    else if (bid < 6144) { bid -= 4096; W = w1;   Wt = t_w1;  K = 1024; N = 2048; bx = bid % 64; by = bid / 64; }
    else                 { bid -= 6144; W = w2;   Wt = t_w2;  K = 2048; N = 1024; bx = bid % 32; by = bid / 32; }
    int f = *flag;
    int n0 = bx * 32, k0 = by * 32;
    int x = threadIdx.x & 31, y = threadIdx.x >> 5;   // (32,8) flat
    #pragma unroll
    for (int r = 0; r < 32; r += 8) {
        size_t idx = (size_t)(k0 + r + y) * N + n0 + x;
        t[r + y][x] = f ? ((const unsigned short*)W)[idx]
                        : f2b(((const float*)W)[idx]);
    }
    __syncthreads();
    #pragma unroll
    for (int r = 0; r < 32; r += 8)
        Wt[(size_t)(n0 + r + y) * K + k0 + x] = t[x][r + y];
}

// ---------- LN1 fused with x canonicalization ----------
__global__ __launch_bounds__(256) void ln1f_k(
    const void* __restrict__ x_raw, const unsigned short* __restrict__ scale,
    const unsigned short* __restrict__ bias, unsigned short* __restrict__ xb,
    unsigned short* __restrict__ xn, const int* __restrict__ flag)
{
    int row = blockIdx.x, tid = threadIdx.x;
    int f = *flag;
    float v[4], s = 0.f, s2 = 0.f;
    #pragma unroll
    for (int i = 0; i < 4; ++i) {
        size_t idx = (size_t)row * D_MODEL + tid + i * 256;
        float t = f ? b2f(((const unsigned short*)x_raw)[idx])
                    : ((const float*)x_raw)[idx];
        v[i] = t; s += t; s2 += t * t;
    }
    #pragma unroll
    for (int off = 32; off; off >>= 1) { s += __shfl_down(s, off); s2 += __shfl_down(s2, off); }
    __shared__ float rs[4], rs2[4];
    int w = tid >> 6;
    if ((tid & 63) == 0) { rs[w] = s; rs2[w] = s2; }
    __syncthreads();
    float S  = rs[0] + rs[1] + rs[2] + rs[3];
    float S2 = rs2[0] + rs2[1] + rs2[2] + rs2[3];
    float mean = S * (1.f / D_MODEL);
    float var  = S2 * (1.f / D_MODEL) - mean * mean;
    float rstd = rsqrtf(var + 1e-6f);
    #pragma unroll
    for (int i = 0; i < 4; ++i) {
        int d = tid + i * 256;
        size_t idx = (size_t)row * D_MODEL + d;
        xb[idx] = f2b(v[i]);
        xn[idx] = f2b((v[i] - mean) * rstd * b2f(scale[d]) + b2f(bias[d]));
    }
}

// ---------- LayerNorm (bf16 in) ----------
__global__ __launch_bounds__(256) void ln_k(
    const unsigned short* __restrict__ x, const unsigned short* __restrict__ scale,
    const unsigned short* __restrict__ bias, unsigned short* __restrict__ out)
{
    int row = blockIdx.x, tid = threadIdx.x;
    const unsigned short* xr = x + (size_t)row * D_MODEL;
    float v[4], s = 0.f, s2 = 0.f;
    #pragma unroll
    for (int i = 0; i < 4; ++i) {
        float t = b2f(xr[tid + i * 256]);
        v[i] = t; s += t; s2 += t * t;
    }
    #pragma unroll
    for (int off = 32; off; off >>= 1) { s += __shfl_down(s, off); s2 += __shfl_down(s2, off); }
    __shared__ float rs[4], rs2[4];
    int w = tid >> 6;
    if ((tid & 63) == 0) { rs[w] = s; rs2[w] = s2; }
    __syncthreads();
    float S  = rs[0] + rs[1] + rs[2] + rs[3];
    float S2 = rs2[0] + rs2[1] + rs2[2] + rs2[3];
    float mean = S * (1.f / D_MODEL);
    float var  = S2 * (1.f / D_MODEL) - mean * mean;
    float rstd = rsqrtf(var + 1e-6f);
    #pragma unroll
    for (int i = 0; i < 4; ++i) {
        int d = tid + i * 256;
        out[(size_t)row * D_MODEL + d] =
            f2b((v[i] - mean) * rstd * b2f(scale[d]) + b2f(bias[d]));
    }
}

// ---------- GEMM: 128xTN tile, BK=64, global_load_lds, XOR swizzle ----------
template<int TN, int ACT, int RES, int ODYN>
__global__ __launch_bounds__(256) void gemm128_k(
    const unsigned short* __restrict__ A, const unsigned short* __restrict__ Bt,
    const unsigned short* __restrict__ bias, const unsigned short* __restrict__ resid,
    void* __restrict__ Cp, int M, int Nn, int K, const int* __restrict__ flag)
{
    constexpr int MT = (TN == 128) ? 4 : 2;
    __shared__ short As[128 * 64];
    __shared__ short Bs[TN * 64];
    int tid = threadIdx.x;
    int m0 = blockIdx.y * 128, n0 = blockIdx.x * TN;
    int lane = tid & 63, w = tid >> 6;
    int a_base = (TN == 128) ? (w >> 1) * 64 : w * 32;
    int b_base = (TN == 128) ? (w & 1) * 64 : 0;
    int mm = lane & 15, q = lane >> 4;

    f32x4 zero = {0.f, 0.f, 0.f, 0.f};
    f32x4 acc[MT][4];
    #pragma unroll
    for (int mt = 0; mt < MT; ++mt)
        #pragma unroll
        for (int nt = 0; nt < 4; ++nt) acc[mt][nt] = zero;

    int grow   = lane >> 3;
    int gchunk = ((lane & 7) ^ grow) * 8;
    const unsigned short* Ab = A  + (size_t)(m0 + w * 32 + grow) * K + gchunk;
    const unsigned short* Bb = Bt + (size_t)(n0 + w * (TN / 4) + grow) * K + gchunk;
    int swz = (mm & 7);

    for (int k0 = 0; k0 < K; k0 += 64) {
        __syncthreads();
        #pragma unroll
        for (int s = 0; s < 4; ++s)
            __builtin_amdgcn_global_load_lds(AS1(Ab + k0 + (size_t)(s * 8) * K),
                                             AS3(&As[(w * 32 + s * 8) * 64]), 16, 0, 0);
        #pragma unroll
        for (int s = 0; s < TN / 32; ++s)
            __builtin_amdgcn_global_load_lds(AS1(Bb + k0 + (size_t)(s * 8) * K),
                                             AS3(&Bs[(w * (TN / 4) + s * 8) * 64]), 16, 0, 0);
        __syncthreads();
        #pragma unroll
        for (int kk = 0; kk < 2; ++kk) {
            int col = ((kk * 4 + q) ^ swz) * 8;
            s8v af[MT], bf[4];
            #pragma unroll
            for (int mt = 0; mt < MT; ++mt)
                af[mt] = *(const s8v*)&As[(a_base + mt * 16 + mm) * 64 + col];
            #pragma unroll
            for (int nt = 0; nt < 4; ++nt)
                bf[nt] = *(const s8v*)&Bs[(b_base + nt * 16 + mm) * 64 + col];
            #pragma unroll
            for (int mt = 0; mt < MT; ++mt)
                #pragma unroll
                for (int nt = 0; nt < 4; ++nt)
                    acc[mt][nt] = __builtin_amdgcn_mfma_f32_16x16x32_bf16(
                        af[mt], bf[nt], acc[mt][nt], 0, 0, 0);
        }
    }

    int f = ODYN ? *flag : 1;
    #pragma unroll
    for (int nt = 0; nt < 4; ++nt) {
        int gc = n0 + b_base + nt * 16 + mm;
        float bv = bias ? b2f(bias[gc]) : 0.f;
        #pragma unroll
        for (int mt = 0; mt < MT; ++mt) {
            #pragma unroll
            for (int r = 0; r < 4; ++r) {
                int gr = m0 + a_base + mt * 16 + q * 4 + r;
                float v = acc[mt][nt][r] + bv;
                if (ACT == 1) v = gelu_f(v);
                if (RES == 1) v += b2f(resid[(size_t)gr * Nn + gc]);
                if (f) ((unsigned short*)Cp)[(size_t)gr * Nn + gc] = f2b(v);
                else   ((float*)Cp)[(size_t)gr * Nn + gc] = v;
            }
        }
    }
}

// ---------- flash attention v3 (round-0 proven) + T5 setprio + exp2 Q-prescale ----
// Scores s = q.k/8 with LN'd inputs: |s| <~ 6, exp(s) overflow-safe.
// Q pre-scaled by 0.125*log2(e) once; softmax uses v_exp_f32 (2^x) directly —
// constant factor cancels in the l-normalization.
// Block = (b,h) x 64 queries, 4 waves; 128-key stages.
__global__ __launch_bounds__(256, 3) void fattn_k(
    const unsigned short* __restrict__ qkv, unsigned short* __restrict__ attn_out)
{
    int bh = blockIdx.x;
    int h = bh & (NHEAD - 1), b = bh >> 4;
    int qt = gridDim.y - 1 - blockIdx.y;          // heaviest first
    int q0 = qt * 64;
    size_t base = (size_t)b * NSEQ * (3 * D_MODEL);

    __shared__ __align__(16) short Ks[128][72];    // [key][dim]
    __shared__ __align__(16) short Vts[64][136];   // [dim][key pair-swizzled]
    __shared__ __align__(16) short Ps[64][136];    // [query][key, col+16*rowquad swizzle]

    int tid = threadIdx.x, lane = tid & 63, w = tid >> 6;
    int mm = lane & 15, q = lane >> 4;

    s8v qf[2];
    #pragma unroll
    for (int kk = 0; kk < 2; ++kk) {
        s8v v = *(const s8v*)(qkv + base + (size_t)(q0 + w * 16 + mm) * (3 * D_MODEL)
                              + h * HSZ + kk * 32 + q * 8);
        #pragma unroll
        for (int e = 0; e < 8; ++e) {   // fold 1/8 and log2(e) into Q once
            float f = b2f((unsigned short)v[e]) * 0.18033688011112042f;
            v[e] = (short)f2b(f);
        }
        qf[kk] = v;
    }

    f32x4 zero = {0.f, 0.f, 0.f, 0.f};
    f32x4 acc_o[4] = {zero, zero, zero, zero};
    float l_acc[4] = {0.f, 0.f, 0.f, 0.f};

    int kr = tid >> 1;            // K staging row 0..127
    int kc = (tid & 1) * 32;      // 0 or 32
    int kp = tid >> 3;            // V key-pair 0..31
    int vd = (tid & 7) * 8;       // V dim base

    const unsigned short* kbase = qkv + base + D_MODEL + h * HSZ;
    const unsigned short* vbase = qkv + base + 2 * D_MODEL + h * HSZ;

    int nstages = (qt + 2) >> 1;

    // prologue: load stage 0 into registers
    s8v kv0, kv1, kv2, kv3, vv0, vv1, vv2, vv3;
    {
        const unsigned short* kb = kbase;
        const unsigned short* vb = vbase;
        kv0 = *(const s8v*)(kb + (size_t)kr * (3 * D_MODEL) + kc);
        kv1 = *(const s8v*)(kb + (size_t)kr * (3 * D_MODEL) + kc + 8);
        kv2 = *(const s8v*)(kb + (size_t)kr * (3 * D_MODEL) + kc + 16);
        kv3 = *(const s8v*)(kb + (size_t)kr * (3 * D_MODEL) + kc + 24);
        vv0 = *(const s8v*)(vb + (size_t)(2 * kp)      * (3 * D_MODEL) + vd);
        vv1 = *(const s8v*)(vb + (size_t)(2 * kp + 1)  * (3 * D_MODEL) + vd);
        vv2 = *(const s8v*)(vb + (size_t)(2 * kp + 64) * (3 * D_MODEL) + vd);
        vv3 = *(const s8v*)(vb + (size_t)(2 * kp + 65) * (3 * D_MODEL) + vd);
    }

    for (int t = 0; t < nstages; ++t) {
        int j0 = t * 128;
        int nsub = (j0 < q0) ? 2 : 1;

        __syncthreads();   // previous stage's LDS readers done
        *(s8v*)&Ks[kr][kc]      = kv0;
        *(s8v*)&Ks[kr][kc + 8]  = kv1;
        *(s8v*)&Ks[kr][kc + 16] = kv2;
        *(s8v*)&Ks[kr][kc + 24] = kv3;
        int c0 = (2 * kp + vd) & 63;
        #pragma unroll
        for (int e = 0; e < 8; ++e) {
            unsigned p0 = (unsigned)(unsigned short)vv0[e] |
                          ((unsigned)(unsigned short)vv1[e] << 16);
            unsigned p1 = (unsigned)(unsigned short)vv2[e] |
                          ((unsigned)(unsigned short)vv3[e] << 16);
            *(unsigned*)&Vts[vd + e][c0]      = p0;
            *(unsigned*)&Vts[vd + e][64 + c0] = p1;
        }
        // prefetch stage t+1 into registers (latency hidden behind compute)
        if (t + 1 < nstages) {
            const unsigned short* kb = kbase + (size_t)(j0 + 128) * (3 * D_MODEL);
            const unsigned short* vb = vbase + (size_t)(j0 + 128) * (3 * D_MODEL);
            kv0 = *(const s8v*)(kb + (size_t)kr * (3 * D_MODEL) + kc);
            kv1 = *(const s8v*)(kb + (size_t)kr * (3 * D_MODEL) + kc + 8);
            kv2 = *(const s8v*)(kb + (size_t)kr * (3 * D_MODEL) + kc + 16);
            kv3 = *(const s8v*)(kb + (size_t)kr * (3 * D_MODEL) + kc + 24);
            vv0 = *(const s8v*)(vb + (size_t)(2 * kp)      * (3 * D_MODEL) + vd);
            vv1 = *(const s8v*)(vb + (size_t)(2 * kp + 1)  * (3 * D_MODEL) + vd);
            vv2 = *(const s8v*)(vb + (size_t)(2 * kp + 64) * (3 * D_MODEL) + vd);
            vv3 = *(const s8v*)(vb + (size_t)(2 * kp + 65) * (3 * D_MODEL) + vd);
        }
        __syncthreads();   // LDS tile ready

        // S = Q K^T over up to 128 keys
        f32x4 sc[8];
        #pragma unroll
        for (int i = 0; i < 8; ++i) sc[i] = zero;
        __builtin_amdgcn_s_setprio(1);
        #pragma unroll
        for (int sub = 0; sub < 2; ++sub) {
            if (sub >= nsub) break;
            #pragma unroll
            for (int kk = 0; kk < 2; ++kk) {
                #pragma unroll
                for (int nt = 0; nt < 4; ++nt) {
                    s8v bv = *(const s8v*)&Ks[sub * 64 + nt * 16 + mm][kk * 32 + q * 8];
                    sc[sub * 4 + nt] = __builtin_amdgcn_mfma_f32_16x16x32_bf16(
                        qf[kk], bv, sc[sub * 4 + nt], 0, 0, 0);
                }
            }
        }
        __builtin_amdgcn_s_setprio(0);

        // p = exp2(s') (s' already includes 1/8*log2e); zero masked; accumulate l; pack P
        int pswz = 16 * q;   // writer row-quad swizzle
        #pragma unroll
        for (int sub = 0; sub < 2; ++sub) {
            if (sub >= nsub) break;
            bool need_mask = (j0 + sub * 64 + 63) > (q0 + w * 16);
            #pragma unroll
            for (int nt = 0; nt < 4; ++nt) {
                int gj = j0 + sub * 64 + nt * 16 + mm;
                #pragma unroll
                for (int r = 0; r < 4; ++r) {
                    float p = __builtin_amdgcn_exp2f(sc[sub * 4 + nt][r]);
                    if (need_mask && gj > (q0 + w * 16 + q * 4 + r)) p = 0.f;
                    l_acc[r] += p;
                    Ps[w * 16 + q * 4 + r][sub * 64 + ((nt * 16 + mm + pswz) & 63)] =
                        (short)f2b_trunc(p);
                }
            }
        }
        // no barrier: each wave reads only its own P rows; Vts/Ks were barriered above

        // O += P V
        int rq16 = 16 * ((mm >> 2) & 3);   // reader row-quad swizzle
        __builtin_amdgcn_s_setprio(1);
        #pragma unroll
        for (int kk4 = 0; kk4 < 4; ++kk4) {
            if (kk4 >= nsub * 2) break;
            int sub = kk4 >> 1, kkl = kk4 & 1;
            s8v av = *(const s8v*)&Ps[w * 16 + mm]
                        [sub * 64 + ((kkl * 32 + q * 8 + rq16) & 63)];
            #pragma unroll
            for (int nt = 0; nt < 4; ++nt) {
                int d = nt * 16 + mm;
                int c = sub * 64 + ((kkl * 32 + q * 8 + (d & 56)) & 63);
                s8v bv = *(const s8v*)&Vts[d][c];
                acc_o[nt] = __builtin_amdgcn_mfma_f32_16x16x32_bf16(av, bv, acc_o[nt], 0, 0, 0);
            }
        }
        __builtin_amdgcn_s_setprio(0);
    }

    // one deferred l reduction across the 16 mm-lanes
    #pragma unroll
    for (int r = 0; r < 4; ++r) {
        #pragma unroll
        for (int msk = 1; msk < 16; msk <<= 1) l_acc[r] += __shfl_xor(l_acc[r], msk);
        l_acc[r] = 1.f / l_acc[r];
    }
    #pragma unroll
    for (int nt = 0; nt < 4; ++nt) {
        int d = nt * 16 + mm;
        #pragma unroll
        for (int r = 0; r < 4; ++r) {
            int row = q0 + w * 16 + q * 4 + r;
            attn_out[(size_t)(b * NSEQ + row) * D_MODEL + h * HSZ + d] =
                f2b(acc_o[nt][r] * l_acc[r]);
        }
    }
}

// ---------- launch ----------
extern "C" void kernel_launch(void* const* d_in, const int* in_sizes, int n_in,
                              void* d_out, int out_size, void* d_ws, size_t ws_size,
                              hipStream_t stream)
{
    const void* x_raw  = d_in[0];
    const void* ln1s_r = d_in[1];
    const void* ln1b_r = d_in[2];
    const void* wqkv_r = d_in[3];
    const void* wout_r = d_in[4];
    const void* bout_r = d_in[5];
    const void* ln2s_r = d_in[6];
    const void* ln2b_r = d_in[7];
    const void* w1_r   = d_in[8];
    const void* b1_r   = d_in[9];
    const void* w2_r   = d_in[10];
    const void* b2_r   = d_in[11];

    char* ws = (char*)d_ws;
    const size_t MB = 1024 * 1024;
    unsigned short* wt_qkv = (unsigned short*)(ws + 0 * MB);
    unsigned short* wt_out = (unsigned short*)(ws + 6 * MB);
    unsigned short* wt_w1  = (unsigned short*)(ws + 8 * MB);
    unsigned short* wt_w2  = (unsigned short*)(ws + 12 * MB);
    unsigned short* xb     = (unsigned short*)(ws + 16 * MB);
    unsigned short* xn     = (unsigned short*)(ws + 24 * MB);
    unsigned short* qkvb   = (unsigned short*)(ws + 32 * MB);
    unsigned short* x1     = (unsigned short*)(ws + 48 * MB);
    int*            flag   = (int*)           (ws + 56 * MB);
    unsigned short* cbias  = (unsigned short*)(ws + 56 * MB + 1024);
    unsigned short* attnb  = xn;
    unsigned short* xn2    = xn;
    unsigned short* hb     = qkvb;

    unsigned short* c_ln1s = cbias + 0;
    unsigned short* c_ln1b = cbias + 1024;
    unsigned short* c_bout = cbias + 2048;
    unsigned short* c_ln2s = cbias + 3072;
    unsigned short* c_ln2b = cbias + 4096;
    unsigned short* c_b1   = cbias + 5120;
    unsigned short* c_b2   = cbias + 7168;

    sniff_k<<<1, 256, 0, stream>>>((const unsigned short*)x_raw, flag);
    cvt_small_k<<<32, 256, 0, stream>>>(ln1s_r, ln1b_r, bout_r, ln2s_r, ln2b_r,
                                        b1_r, b2_r, cbias, flag);
    transpose_all_k<<<8192, 256, 0, stream>>>(wqkv_r, wout_r, w1_r, w2_r,
                                              wt_qkv, wt_out, wt_w1, wt_w2, flag);
    ln1f_k<<<MROWS, 256, 0, stream>>>(x_raw, c_ln1s, c_ln1b, xb, xn, flag);
    gemm128_k<128, 0, 0, 0><<<dim3(24, 32), 256, 0, stream>>>(
        xn, wt_qkv, nullptr, nullptr, qkvb, MROWS, 3072, 1024, flag);
    fattn_k<<<dim3(NBATCH * NHEAD, NSEQ / 64), 256, 0, stream>>>(qkvb, attnb);
    gemm128_k<64, 0, 1, 0><<<dim3(16, 32), 256, 0, stream>>>(
        attnb, wt_out, c_bout, xb, x1, MROWS, 1024, 1024, flag);
    ln_k<<<MROWS, 256, 0, stream>>>(x1, c_ln2s, c_ln2b, xn2);
    gemm128_k<128, 1, 0, 0><<<dim3(16, 32), 256, 0, stream>>>(
        xn2, wt_w1, c_b1, nullptr, hb, MROWS, 2048, 1024, flag);
    gemm128_k<64, 0, 1, 1><<<dim3(16, 32), 256, 0, stream>>>(
        hb, wt_w2, c_b2, x1, d_out, MROWS, 1024, 2048, flag);
}

// Round 9
// 298.215 us; speedup vs baseline: 1.0587x; 1.0151x over previous
//
#include <hip/hip_runtime.h>

// B=2, N=2048, D=1024, H=16, HS=64.
#define D_MODEL 1024
#define NSEQ    2048
#define NBATCH  2
#define NHEAD   16
#define HSZ     64
#define MROWS   4096   // B*N

typedef short s8v  __attribute__((ext_vector_type(8)));   // 8 x bf16 (bit-pattern shorts)
typedef float f32x4 __attribute__((ext_vector_type(4)));

#define AS1(p) ((__attribute__((address_space(1))) const void*)(p))
#define AS3(p) ((__attribute__((address_space(3))) void*)(p))

__device__ __forceinline__ float b2f(unsigned short s) {
    union { unsigned u; float f; } z; z.u = (unsigned)s << 16; return z.f;
}
__device__ __forceinline__ unsigned short f2b(float f) {
    union { float f; unsigned u; } z; z.f = f;
    unsigned r = z.u + 0x7fffu + ((z.u >> 16) & 1u);   // RNE
    return (unsigned short)(r >> 16);
}
__device__ __forceinline__ unsigned short f2b_trunc(float f) {
    union { float f; unsigned u; } z; z.f = f;
    return (unsigned short)(z.u >> 16);
}
__device__ __forceinline__ float gelu_f(float x) {
    float u = 0.7978845608028654f * (x + 0.044715f * x * x * x);
    float t = 1.f - 2.f / (1.f + __expf(2.f * u));     // tanh(u), saturating
    return 0.5f * x * (1.f + t);
}

// ---------- dtype sniff ----------
__global__ __launch_bounds__(256) void sniff_k(const unsigned short* __restrict__ xr,
                                               int* __restrict__ flag) {
    __shared__ int cnt[4];
    int tid = threadIdx.x, ok = 0;
    for (int i = tid; i < 2048; i += 256) {
        unsigned short u = xr[i];
        int e = (u >> 7) & 0xFF;
        if (u == 0 || (e >= 110 && e <= 135)) ok++;
    }
    #pragma unroll
    for (int off = 32; off; off >>= 1) ok += __shfl_down(ok, off);
    if ((tid & 63) == 0) cnt[tid >> 6] = ok;
    __syncthreads();
    if (tid == 0) {
        int tot = cnt[0] + cnt[1] + cnt[2] + cnt[3];
        *flag = (tot > 1843) ? 1 : 0;
    }
}

// ---------- all 7 small vectors in one launch ----------
__global__ __launch_bounds__(256) void cvt_small_k(
    const void* p0, const void* p1, const void* p2, const void* p3,
    const void* p4, const void* p5, const void* p6,
    unsigned short* __restrict__ out, const int* __restrict__ flag)
{
    int i = blockIdx.x * 256 + threadIdx.x;   // 0..8191
    const void* src; int off;
    if      (i < 1024) { src = p0; off = i; }
    else if (i < 2048) { src = p1; off = i - 1024; }
    else if (i < 3072) { src = p2; off = i - 2048; }
    else if (i < 4096) { src = p3; off = i - 3072; }
    else if (i < 5120) { src = p4; off = i - 4096; }
    else if (i < 7168) { src = p5; off = i - 5120; }
    else               { src = p6; off = i - 7168; }
    out[i] = (*flag) ? ((const unsigned short*)src)[off]
                     : f2b(((const float*)src)[off]);
}

// ---------- all 4 weight transposes in one launch ----------
__global__ __launch_bounds__(256) void transpose_all_k(
    const void* wqkv, const void* wout, const void* w1, const void* w2,
    unsigned short* t_qkv, unsigned short* t_out,
    unsigned short* t_w1, unsigned short* t_w2, const int* __restrict__ flag)
{
    __shared__ unsigned short t[32][33];
    int bid = blockIdx.x;
    const void* W; unsigned short* Wt; int K, N, bx, by;
    if      (bid < 3072) { W = wqkv; Wt = t_qkv; K = 1024; N = 3072; bx = bid % 96; by = bid / 96; }
    else if (bid < 4096) { bid -= 3072; W = wout; Wt = t_out; K = 1024; N = 1024; bx = bid % 32; by = bid / 32; }
    else if (bid < 6144) { bid -= 4096; W = w1;   Wt = t_w1;  K = 1024; N = 2048; bx = bid % 64; by = bid / 64; }
    else                 { bid -= 6144; W = w2;   Wt = t_w2;  K = 2048; N = 1024; bx = bid % 32; by = bid / 32; }
    int f = *flag;
    int n0 = bx * 32, k0 = by * 32;
    int x = threadIdx.x & 31, y = threadIdx.x >> 5;   // (32,8) flat
    #pragma unroll
    for (int r = 0; r < 32; r += 8) {
        size_t idx = (size_t)(k0 + r + y) * N + n0 + x;
        t[r + y][x] = f ? ((const unsigned short*)W)[idx]
                        : f2b(((const float*)W)[idx]);
    }
    __syncthreads();
    #pragma unroll
    for (int r = 0; r < 32; r += 8)
        Wt[(size_t)(n0 + r + y) * K + k0 + x] = t[x][r + y];
}

// ---------- LN1 fused with x canonicalization ----------
__global__ __launch_bounds__(256) void ln1f_k(
    const void* __restrict__ x_raw, const unsigned short* __restrict__ scale,
    const unsigned short* __restrict__ bias, unsigned short* __restrict__ xb,
    unsigned short* __restrict__ xn, const int* __restrict__ flag)
{
    int row = blockIdx.x, tid = threadIdx.x;
    int f = *flag;
    float v[4], s = 0.f, s2 = 0.f;
    #pragma unroll
    for (int i = 0; i < 4; ++i) {
        size_t idx = (size_t)row * D_MODEL + tid + i * 256;
        float t = f ? b2f(((const unsigned short*)x_raw)[idx])
                    : ((const float*)x_raw)[idx];
        v[i] = t; s += t; s2 += t * t;
    }
    #pragma unroll
    for (int off = 32; off; off >>= 1) { s += __shfl_down(s, off); s2 += __shfl_down(s2, off); }
    __shared__ float rs[4], rs2[4];
    int w = tid >> 6;
    if ((tid & 63) == 0) { rs[w] = s; rs2[w] = s2; }
    __syncthreads();
    float S  = rs[0] + rs[1] + rs[2] + rs[3];
    float S2 = rs2[0] + rs2[1] + rs2[2] + rs2[3];
    float mean = S * (1.f / D_MODEL);
    float var  = S2 * (1.f / D_MODEL) - mean * mean;
    float rstd = rsqrtf(var + 1e-6f);
    #pragma unroll
    for (int i = 0; i < 4; ++i) {
        int d = tid + i * 256;
        size_t idx = (size_t)row * D_MODEL + d;
        xb[idx] = f2b(v[i]);
        xn[idx] = f2b((v[i] - mean) * rstd * b2f(scale[d]) + b2f(bias[d]));
    }
}

// ---------- LayerNorm (bf16 in) ----------
__global__ __launch_bounds__(256) void ln_k(
    const unsigned short* __restrict__ x, const unsigned short* __restrict__ scale,
    const unsigned short* __restrict__ bias, unsigned short* __restrict__ out)
{
    int row = blockIdx.x, tid = threadIdx.x;
    const unsigned short* xr = x + (size_t)row * D_MODEL;
    float v[4], s = 0.f, s2 = 0.f;
    #pragma unroll
    for (int i = 0; i < 4; ++i) {
        float t = b2f(xr[tid + i * 256]);
        v[i] = t; s += t; s2 += t * t;
    }
    #pragma unroll
    for (int off = 32; off; off >>= 1) { s += __shfl_down(s, off); s2 += __shfl_down(s2, off); }
    __shared__ float rs[4], rs2[4];
    int w = tid >> 6;
    if ((tid & 63) == 0) { rs[w] = s; rs2[w] = s2; }
    __syncthreads();
    float S  = rs[0] + rs[1] + rs[2] + rs[3];
    float S2 = rs2[0] + rs2[1] + rs2[2] + rs2[3];
    float mean = S * (1.f / D_MODEL);
    float var  = S2 * (1.f / D_MODEL) - mean * mean;
    float rstd = rsqrtf(var + 1e-6f);
    #pragma unroll
    for (int i = 0; i < 4; ++i) {
        int d = tid + i * 256;
        out[(size_t)row * D_MODEL + d] =
            f2b((v[i] - mean) * rstd * b2f(scale[d]) + b2f(bias[d]));
    }
}

// ---------- GEMM: 128xTN tile, BK=64, global_load_lds, XOR swizzle ----------
template<int TN, int ACT, int RES, int ODYN>
__global__ __launch_bounds__(256) void gemm128_k(
    const unsigned short* __restrict__ A, const unsigned short* __restrict__ Bt,
    const unsigned short* __restrict__ bias, const unsigned short* __restrict__ resid,
    void* __restrict__ Cp, int M, int Nn, int K, const int* __restrict__ flag)
{
    constexpr int MT = (TN == 128) ? 4 : 2;
    __shared__ short As[128 * 64];
    __shared__ short Bs[TN * 64];
    int tid = threadIdx.x;
    int m0 = blockIdx.y * 128, n0 = blockIdx.x * TN;
    int lane = tid & 63, w = tid >> 6;
    int a_base = (TN == 128) ? (w >> 1) * 64 : w * 32;
    int b_base = (TN == 128) ? (w & 1) * 64 : 0;
    int mm = lane & 15, q = lane >> 4;

    f32x4 zero = {0.f, 0.f, 0.f, 0.f};
    f32x4 acc[MT][4];
    #pragma unroll
    for (int mt = 0; mt < MT; ++mt)
        #pragma unroll
        for (int nt = 0; nt < 4; ++nt) acc[mt][nt] = zero;

    int grow   = lane >> 3;
    int gchunk = ((lane & 7) ^ grow) * 8;
    const unsigned short* Ab = A  + (size_t)(m0 + w * 32 + grow) * K + gchunk;
    const unsigned short* Bb = Bt + (size_t)(n0 + w * (TN / 4) + grow) * K + gchunk;
    int swz = (mm & 7);

    for (int k0 = 0; k0 < K; k0 += 64) {
        __syncthreads();
        #pragma unroll
        for (int s = 0; s < 4; ++s)
            __builtin_amdgcn_global_load_lds(AS1(Ab + k0 + (size_t)(s * 8) * K),
                                             AS3(&As[(w * 32 + s * 8) * 64]), 16, 0, 0);
        #pragma unroll
        for (int s = 0; s < TN / 32; ++s)
            __builtin_amdgcn_global_load_lds(AS1(Bb + k0 + (size_t)(s * 8) * K),
                                             AS3(&Bs[(w * (TN / 4) + s * 8) * 64]), 16, 0, 0);
        __syncthreads();
        #pragma unroll
        for (int kk = 0; kk < 2; ++kk) {
            int col = ((kk * 4 + q) ^ swz) * 8;
            s8v af[MT], bf[4];
            #pragma unroll
            for (int mt = 0; mt < MT; ++mt)
                af[mt] = *(const s8v*)&As[(a_base + mt * 16 + mm) * 64 + col];
            #pragma unroll
            for (int nt = 0; nt < 4; ++nt)
                bf[nt] = *(const s8v*)&Bs[(b_base + nt * 16 + mm) * 64 + col];
            #pragma unroll
            for (int mt = 0; mt < MT; ++mt)
                #pragma unroll
                for (int nt = 0; nt < 4; ++nt)
                    acc[mt][nt] = __builtin_amdgcn_mfma_f32_16x16x32_bf16(
                        af[mt], bf[nt], acc[mt][nt], 0, 0, 0);
        }
    }

    int f = ODYN ? *flag : 1;
    #pragma unroll
    for (int nt = 0; nt < 4; ++nt) {
        int gc = n0 + b_base + nt * 16 + mm;
        float bv = bias ? b2f(bias[gc]) : 0.f;
        #pragma unroll
        for (int mt = 0; mt < MT; ++mt) {
            #pragma unroll
            for (int r = 0; r < 4; ++r) {
                int gr = m0 + a_base + mt * 16 + q * 4 + r;
                float v = acc[mt][nt][r] + bv;
                if (ACT == 1) v = gelu_f(v);
                if (RES == 1) v += b2f(resid[(size_t)gr * Nn + gc]);
                if (f) ((unsigned short*)Cp)[(size_t)gr * Nn + gc] = f2b(v);
                else   ((float*)Cp)[(size_t)gr * Nn + gc] = v;
            }
        }
    }
}

// ---------- flash attention v8: round-0 structure + Ps-aliases-Ks + MFMA l ----------
// Scores s = q.k/8 with LN'd inputs: |s| <~ 6, exp overflow-safe.
// Q pre-scaled by 0.125*log2(e) once; softmax = v_exp_f32 (2^x) directly.
// Ps reuses Ks storage (Ks dead after QK^T; barrier between QK^T and P-store)
// -> LDS 53k -> 35k -> 4 blocks/CU. l computed on the MFMA pipe via an extra
// mfma(P, ones) per PV step (B = constant 1.0 fragment) -> no VALU l-adds, no
// epilogue cross-lane reduce, and l matches the exact bf16 P used for O.
// Block = (b,h) x 64 queries, 4 waves; 128-key stages.
__global__ __launch_bounds__(256, 4) void fattn_k(
    const unsigned short* __restrict__ qkv, unsigned short* __restrict__ attn_out)
{
    int bh = blockIdx.x;
    int h = bh & (NHEAD - 1), b = bh >> 4;
    int qt = gridDim.y - 1 - blockIdx.y;          // heaviest first
    int q0 = qt * 64;
    size_t base = (size_t)b * NSEQ * (3 * D_MODEL);

    __shared__ __align__(16) short Ks[128][72];    // [key][dim]; P aliases this after QK^T
    __shared__ __align__(16) short Vts[64][136];   // [dim][key pair-swizzled]
    short (*Ps)[136] = (short(*)[136])&Ks[0][0];   // [query][key, col+16*rowquad swizzle]

    int tid = threadIdx.x, lane = tid & 63, w = tid >> 6;
    int mm = lane & 15, q = lane >> 4;

    s8v qf[2];
    #pragma unroll
    for (int kk = 0; kk < 2; ++kk) {
        s8v v = *(const s8v*)(qkv + base + (size_t)(q0 + w * 16 + mm) * (3 * D_MODEL)
                              + h * HSZ + kk * 32 + q * 8);
        #pragma unroll
        for (int e = 0; e < 8; ++e) {   // fold 1/8 and log2(e) into Q once
            float f = b2f((unsigned short)v[e]) * 0.18033688011112042f;
            v[e] = (short)f2b(f);
        }
        qf[kk] = v;
    }

    s8v ones;                            // constant bf16 1.0 B-fragment for l-MFMA
    #pragma unroll
    for (int e = 0; e < 8; ++e) ones[e] = (short)0x3F80;

    f32x4 zero = {0.f, 0.f, 0.f, 0.f};
    f32x4 acc_o[4] = {zero, zero, zero, zero};
    f32x4 acc_l = zero;                  // l on the MFMA pipe

    int kr = tid >> 1;            // K staging row 0..127
    int kc = (tid & 1) * 32;      // 0 or 32
    int kp = tid >> 3;            // V key-pair 0..31
    int vd = (tid & 7) * 8;       // V dim base

    const unsigned short* kbase = qkv + base + D_MODEL + h * HSZ;
    const unsigned short* vbase = qkv + base + 2 * D_MODEL + h * HSZ;

    int nstages = (qt + 2) >> 1;

    // prologue: load stage 0 into registers
    s8v kv0, kv1, kv2, kv3, vv0, vv1, vv2, vv3;
    {
        const unsigned short* kb = kbase;
        const unsigned short* vb = vbase;
        kv0 = *(const s8v*)(kb + (size_t)kr * (3 * D_MODEL) + kc);
        kv1 = *(const s8v*)(kb + (size_t)kr * (3 * D_MODEL) + kc + 8);
        kv2 = *(const s8v*)(kb + (size_t)kr * (3 * D_MODEL) + kc + 16);
        kv3 = *(const s8v*)(kb + (size_t)kr * (3 * D_MODEL) + kc + 24);
        vv0 = *(const s8v*)(vb + (size_t)(2 * kp)      * (3 * D_MODEL) + vd);
        vv1 = *(const s8v*)(vb + (size_t)(2 * kp + 1)  * (3 * D_MODEL) + vd);
        vv2 = *(const s8v*)(vb + (size_t)(2 * kp + 64) * (3 * D_MODEL) + vd);
        vv3 = *(const s8v*)(vb + (size_t)(2 * kp + 65) * (3 * D_MODEL) + vd);
    }

    for (int t = 0; t < nstages; ++t) {
        int j0 = t * 128;
        int nsub = (j0 < q0) ? 2 : 1;

        __syncthreads();   // previous stage's LDS readers (PV on Ps/Vts) done
        *(s8v*)&Ks[kr][kc]      = kv0;
        *(s8v*)&Ks[kr][kc + 8]  = kv1;
        *(s8v*)&Ks[kr][kc + 16] = kv2;
        *(s8v*)&Ks[kr][kc + 24] = kv3;
        int c0 = (2 * kp + vd) & 63;
        #pragma unroll
        for (int e = 0; e < 8; ++e) {
            unsigned p0 = (unsigned)(unsigned short)vv0[e] |
                          ((unsigned)(unsigned short)vv1[e] << 16);
            unsigned p1 = (unsigned)(unsigned short)vv2[e] |
                          ((unsigned)(unsigned short)vv3[e] << 16);
            *(unsigned*)&Vts[vd + e][c0]      = p0;
            *(unsigned*)&Vts[vd + e][64 + c0] = p1;
        }
        // prefetch stage t+1 into registers (latency hidden behind compute)
        if (t + 1 < nstages) {
            const unsigned short* kb = kbase + (size_t)(j0 + 128) * (3 * D_MODEL);
            const unsigned short* vb = vbase + (size_t)(j0 + 128) * (3 * D_MODEL);
            kv0 = *(const s8v*)(kb + (size_t)kr * (3 * D_MODEL) + kc);
            kv1 = *(const s8v*)(kb + (size_t)kr * (3 * D_MODEL) + kc + 8);
            kv2 = *(const s8v*)(kb + (size_t)kr * (3 * D_MODEL) + kc + 16);
            kv3 = *(const s8v*)(kb + (size_t)kr * (3 * D_MODEL) + kc + 24);
            vv0 = *(const s8v*)(vb + (size_t)(2 * kp)      * (3 * D_MODEL) + vd);
            vv1 = *(const s8v*)(vb + (size_t)(2 * kp + 1)  * (3 * D_MODEL) + vd);
            vv2 = *(const s8v*)(vb + (size_t)(2 * kp + 64) * (3 * D_MODEL) + vd);
            vv3 = *(const s8v*)(vb + (size_t)(2 * kp + 65) * (3 * D_MODEL) + vd);
        }
        __syncthreads();   // LDS tile ready

        // S = Q K^T over up to 128 keys
        f32x4 sc[8];
        #pragma unroll
        for (int i = 0; i < 8; ++i) sc[i] = zero;
        __builtin_amdgcn_s_setprio(1);
        #pragma unroll
        for (int sub = 0; sub < 2; ++sub) {
            if (sub >= nsub) break;
            #pragma unroll
            for (int kk = 0; kk < 2; ++kk) {
                #pragma unroll
                for (int nt = 0; nt < 4; ++nt) {
                    s8v bv = *(const s8v*)&Ks[sub * 64 + nt * 16 + mm][kk * 32 + q * 8];
                    sc[sub * 4 + nt] = __builtin_amdgcn_mfma_f32_16x16x32_bf16(
                        qf[kk], bv, sc[sub * 4 + nt], 0, 0, 0);
                }
            }
        }
        __builtin_amdgcn_s_setprio(0);

        __syncthreads();   // all waves' QK^T reads of Ks done before P overwrites it

        // p = exp2(s') (s' already includes 1/8*log2e); zero masked; pack P
        int pswz = 16 * q;   // writer row-quad swizzle
        #pragma unroll
        for (int sub = 0; sub < 2; ++sub) {
            if (sub >= nsub) break;
            bool need_mask = (j0 + sub * 64 + 63) > (q0 + w * 16);
            #pragma unroll
            for (int nt = 0; nt < 4; ++nt) {
                int gj = j0 + sub * 64 + nt * 16 + mm;
                #pragma unroll
                for (int r = 0; r < 4; ++r) {
                    float p = __builtin_amdgcn_exp2f(sc[sub * 4 + nt][r]);
                    if (need_mask && gj > (q0 + w * 16 + q * 4 + r)) p = 0.f;
                    Ps[w * 16 + q * 4 + r][sub * 64 + ((nt * 16 + mm + pswz) & 63)] =
                        (short)f2b_trunc(p);
                }
            }
        }
        // no barrier: each wave reads only its own P rows; Vts was barriered above

        // O += P V ; l += P . ones  (l on the MFMA pipe)
        int rq16 = 16 * ((mm >> 2) & 3);   // reader row-quad swizzle
        __builtin_amdgcn_s_setprio(1);
        #pragma unroll
        for (int kk4 = 0; kk4 < 4; ++kk4) {
            if (kk4 >= nsub * 2) break;
            int sub = kk4 >> 1, kkl = kk4 & 1;
            s8v av = *(const s8v*)&Ps[w * 16 + mm]
                        [sub * 64 + ((kkl * 32 + q * 8 + rq16) & 63)];
            #pragma unroll
            for (int nt = 0; nt < 4; ++nt) {
                int d = nt * 16 + mm;
                int c = sub * 64 + ((kkl * 32 + q * 8 + (d & 56)) & 63);
                s8v bv = *(const s8v*)&Vts[d][c];
                acc_o[nt] = __builtin_amdgcn_mfma_f32_16x16x32_bf16(av, bv, acc_o[nt], 0, 0, 0);
            }
            acc_l = __builtin_amdgcn_mfma_f32_16x16x32_bf16(av, ones, acc_l, 0, 0, 0);
        }
        __builtin_amdgcn_s_setprio(0);
    }

    // acc_l[r] already holds the full row sum (every output col identical)
    #pragma unroll
    for (int nt = 0; nt < 4; ++nt) {
        int d = nt * 16 + mm;
        #pragma unroll
        for (int r = 0; r < 4; ++r) {
            int row = q0 + w * 16 + q * 4 + r;
            attn_out[(size_t)(b * NSEQ + row) * D_MODEL + h * HSZ + d] =
                f2b(acc_o[nt][r] / acc_l[r]);
        }
    }
}

// ---------- launch ----------
extern "C" void kernel_launch(void* const* d_in, const int* in_sizes, int n_in,
                              void* d_out, int out_size, void* d_ws, size_t ws_size,
                              hipStream_t stream)
{
    const void* x_raw  = d_in[0];
    const void* ln1s_r = d_in[1];
    const void* ln1b_r = d_in[2];
    const void* wqkv_r = d_in[3];
    const void* wout_r = d_in[4];
    const void* bout_r = d_in[5];
    const void* ln2s_r = d_in[6];
    const void* ln2b_r = d_in[7];
    const void* w1_r   = d_in[8];
    const void* b1_r   = d_in[9];
    const void* w2_r   = d_in[10];
    const void* b2_r   = d_in[11];

    char* ws = (char*)d_ws;
    const size_t MB = 1024 * 1024;
    unsigned short* wt_qkv = (unsigned short*)(ws + 0 * MB);
    unsigned short* wt_out = (unsigned short*)(ws + 6 * MB);
    unsigned short* wt_w1  = (unsigned short*)(ws + 8 * MB);
    unsigned short* wt_w2  = (unsigned short*)(ws + 12 * MB);
    unsigned short* xb     = (unsigned short*)(ws + 16 * MB);
    unsigned short* xn     = (unsigned short*)(ws + 24 * MB);
    unsigned short* qkvb   = (unsigned short*)(ws + 32 * MB);
    unsigned short* x1     = (unsigned short*)(ws + 48 * MB);
    int*            flag   = (int*)           (ws + 56 * MB);
    unsigned short* cbias  = (unsigned short*)(ws + 56 * MB + 1024);
    unsigned short* attnb  = xn;
    unsigned short* xn2    = xn;
    unsigned short* hb     = qkvb;

    unsigned short* c_ln1s = cbias + 0;
    unsigned short* c_ln1b = cbias + 1024;
    unsigned short* c_bout = cbias + 2048;
    unsigned short* c_ln2s = cbias + 3072;
    unsigned short* c_ln2b = cbias + 4096;
    unsigned short* c_b1   = cbias + 5120;
    unsigned short* c_b2   = cbias + 7168;

    sniff_k<<<1, 256, 0, stream>>>((const unsigned short*)x_raw, flag);
    cvt_small_k<<<32, 256, 0, stream>>>(ln1s_r, ln1b_r, bout_r, ln2s_r, ln2b_r,
                                        b1_r, b2_r, cbias, flag);
    transpose_all_k<<<8192, 256, 0, stream>>>(wqkv_r, wout_r, w1_r, w2_r,
                                              wt_qkv, wt_out, wt_w1, wt_w2, flag);
    ln1f_k<<<MROWS, 256, 0, stream>>>(x_raw, c_ln1s, c_ln1b, xb, xn, flag);
    gemm128_k<128, 0, 0, 0><<<dim3(24, 32), 256, 0, stream>>>(
        xn, wt_qkv, nullptr, nullptr, qkvb, MROWS, 3072, 1024, flag);
    fattn_k<<<dim3(NBATCH * NHEAD, NSEQ / 64), 256, 0, stream>>>(qkvb, attnb);
    gemm128_k<64, 0, 1, 0><<<dim3(16, 32), 256, 0, stream>>>(
        attnb, wt_out, c_bout, xb, x1, MROWS, 1024, 1024, flag);
    ln_k<<<MROWS, 256, 0, stream>>>(x1, c_ln2s, c_ln2b, xn2);
    gemm128_k<128, 1, 0, 0><<<dim3(16, 32), 256, 0, stream>>>(
        xn2, wt_w1, c_b1, nullptr, hb, MROWS, 2048, 1024, flag);
    gemm128_k<64, 0, 1, 1><<<dim3(16, 32), 256, 0, stream>>>(
        hb, wt_w2, c_b2, x1, d_out, MROWS, 1024, 2048, flag);
}

// Round 10
// 291.443 us; speedup vs baseline: 1.0833x; 1.0232x over previous
//
#include <hip/hip_runtime.h>

// B=2, N=2048, D=1024, H=16, HS=64.
#define D_MODEL 1024
#define NSEQ    2048
#define NBATCH  2
#define NHEAD   16
#define HSZ     64
#define MROWS   4096   // B*N

typedef short s8v  __attribute__((ext_vector_type(8)));   // 8 x bf16 (bit-pattern shorts)
typedef float f32x4 __attribute__((ext_vector_type(4)));

#define AS1(p) ((__attribute__((address_space(1))) const void*)(p))
#define AS3(p) ((__attribute__((address_space(3))) void*)(p))

__device__ __forceinline__ float b2f(unsigned short s) {
    union { unsigned u; float f; } z; z.u = (unsigned)s << 16; return z.f;
}
__device__ __forceinline__ unsigned short f2b(float f) {
    union { float f; unsigned u; } z; z.f = f;
    unsigned r = z.u + 0x7fffu + ((z.u >> 16) & 1u);   // RNE
    return (unsigned short)(r >> 16);
}
__device__ __forceinline__ unsigned short f2b_trunc(float f) {
    union { float f; unsigned u; } z; z.f = f;
    return (unsigned short)(z.u >> 16);
}
__device__ __forceinline__ float gelu_f(float x) {
    float u = 0.7978845608028654f * (x + 0.044715f * x * x * x);
    float t = 1.f - 2.f / (1.f + __expf(2.f * u));     // tanh(u), saturating
    return 0.5f * x * (1.f + t);
}

// ---------- dtype sniff ----------
__global__ __launch_bounds__(256) void sniff_k(const unsigned short* __restrict__ xr,
                                               int* __restrict__ flag) {
    __shared__ int cnt[4];
    int tid = threadIdx.x, ok = 0;
    for (int i = tid; i < 2048; i += 256) {
        unsigned short u = xr[i];
        int e = (u >> 7) & 0xFF;
        if (u == 0 || (e >= 110 && e <= 135)) ok++;
    }
    #pragma unroll
    for (int off = 32; off; off >>= 1) ok += __shfl_down(ok, off);
    if ((tid & 63) == 0) cnt[tid >> 6] = ok;
    __syncthreads();
    if (tid == 0) {
        int tot = cnt[0] + cnt[1] + cnt[2] + cnt[3];
        *flag = (tot > 1843) ? 1 : 0;
    }
}

// ---------- all 7 small vectors in one launch ----------
__global__ __launch_bounds__(256) void cvt_small_k(
    const void* p0, const void* p1, const void* p2, const void* p3,
    const void* p4, const void* p5, const void* p6,
    unsigned short* __restrict__ out, const int* __restrict__ flag)
{
    int i = blockIdx.x * 256 + threadIdx.x;   // 0..8191
    const void* src; int off;
    if      (i < 1024) { src = p0; off = i; }
    else if (i < 2048) { src = p1; off = i - 1024; }
    else if (i < 3072) { src = p2; off = i - 2048; }
    else if (i < 4096) { src = p3; off = i - 3072; }
    else if (i < 5120) { src = p4; off = i - 4096; }
    else if (i < 7168) { src = p5; off = i - 5120; }
    else               { src = p6; off = i - 7168; }
    out[i] = (*flag) ? ((const unsigned short*)src)[off]
                     : f2b(((const float*)src)[off]);
}

// ---------- all 4 weight transposes in one launch ----------
__global__ __launch_bounds__(256) void transpose_all_k(
    const void* wqkv, const void* wout, const void* w1, const void* w2,
    unsigned short* t_qkv, unsigned short* t_out,
    unsigned short* t_w1, unsigned short* t_w2, const int* __restrict__ flag)
{
    __shared__ unsigned short t[32][33];
    int bid = blockIdx.x;
    const void* W; unsigned short* Wt; int K, N, bx, by;
    if      (bid < 3072) { W = wqkv; Wt = t_qkv; K = 1024; N = 3072; bx = bid % 96; by = bid / 96; }
    else if (bid < 4096) { bid -= 3072; W = wout; Wt = t_out; K = 1024; N = 1024; bx = bid % 32; by = bid / 32; }
    else if (bid < 6144) { bid -= 4096; W = w1;   Wt = t_w1;  K = 1024; N = 2048; bx = bid % 64; by = bid / 64; }
    else                 { bid -= 6144; W = w2;   Wt = t_w2;  K = 2048; N = 1024; bx = bid % 32; by = bid / 32; }
    int f = *flag;
    int n0 = bx * 32, k0 = by * 32;
    int x = threadIdx.x & 31, y = threadIdx.x >> 5;   // (32,8) flat
    #pragma unroll
    for (int r = 0; r < 32; r += 8) {
        size_t idx = (size_t)(k0 + r + y) * N + n0 + x;
        t[r + y][x] = f ? ((const unsigned short*)W)[idx]
                        : f2b(((const float*)W)[idx]);
    }
    __syncthreads();
    #pragma unroll
    for (int r = 0; r < 32; r += 8)
        Wt[(size_t)(n0 + r + y) * K + k0 + x] = t[x][r + y];
}

// ---------- LN1 fused with x canonicalization ----------
__global__ __launch_bounds__(256) void ln1f_k(
    const void* __restrict__ x_raw, const unsigned short* __restrict__ scale,
    const unsigned short* __restrict__ bias, unsigned short* __restrict__ xb,
    unsigned short* __restrict__ xn, const int* __restrict__ flag)
{
    int row = blockIdx.x, tid = threadIdx.x;
    int f = *flag;
    float v[4], s = 0.f, s2 = 0.f;
    #pragma unroll
    for (int i = 0; i < 4; ++i) {
        size_t idx = (size_t)row * D_MODEL + tid + i * 256;
        float t = f ? b2f(((const unsigned short*)x_raw)[idx])
                    : ((const float*)x_raw)[idx];
        v[i] = t; s += t; s2 += t * t;
    }
    #pragma unroll
    for (int off = 32; off; off >>= 1) { s += __shfl_down(s, off); s2 += __shfl_down(s2, off); }
    __shared__ float rs[4], rs2[4];
    int w = tid >> 6;
    if ((tid & 63) == 0) { rs[w] = s; rs2[w] = s2; }
    __syncthreads();
    float S  = rs[0] + rs[1] + rs[2] + rs[3];
    float S2 = rs2[0] + rs2[1] + rs2[2] + rs2[3];
    float mean = S * (1.f / D_MODEL);
    float var  = S2 * (1.f / D_MODEL) - mean * mean;
    float rstd = rsqrtf(var + 1e-6f);
    #pragma unroll
    for (int i = 0; i < 4; ++i) {
        int d = tid + i * 256;
        size_t idx = (size_t)row * D_MODEL + d;
        xb[idx] = f2b(v[i]);
        xn[idx] = f2b((v[i] - mean) * rstd * b2f(scale[d]) + b2f(bias[d]));
    }
}

// ---------- LayerNorm (bf16 in) ----------
__global__ __launch_bounds__(256) void ln_k(
    const unsigned short* __restrict__ x, const unsigned short* __restrict__ scale,
    const unsigned short* __restrict__ bias, unsigned short* __restrict__ out)
{
    int row = blockIdx.x, tid = threadIdx.x;
    const unsigned short* xr = x + (size_t)row * D_MODEL;
    float v[4], s = 0.f, s2 = 0.f;
    #pragma unroll
    for (int i = 0; i < 4; ++i) {
        float t = b2f(xr[tid + i * 256]);
        v[i] = t; s += t; s2 += t * t;
    }
    #pragma unroll
    for (int off = 32; off; off >>= 1) { s += __shfl_down(s, off); s2 += __shfl_down(s2, off); }
    __shared__ float rs[4], rs2[4];
    int w = tid >> 6;
    if ((tid & 63) == 0) { rs[w] = s; rs2[w] = s2; }
    __syncthreads();
    float S  = rs[0] + rs[1] + rs[2] + rs[3];
    float S2 = rs2[0] + rs2[1] + rs2[2] + rs2[3];
    float mean = S * (1.f / D_MODEL);
    float var  = S2 * (1.f / D_MODEL) - mean * mean;
    float rstd = rsqrtf(var + 1e-6f);
    #pragma unroll
    for (int i = 0; i < 4; ++i) {
        int d = tid + i * 256;
        out[(size_t)row * D_MODEL + d] =
            f2b((v[i] - mean) * rstd * b2f(scale[d]) + b2f(bias[d]));
    }
}

// ---------- GEMM: 128xTN tile, BK=64, global_load_lds, XOR swizzle ----------
template<int TN, int ACT, int RES, int ODYN>
__global__ __launch_bounds__(256) void gemm128_k(
    const unsigned short* __restrict__ A, const unsigned short* __restrict__ Bt,
    const unsigned short* __restrict__ bias, const unsigned short* __restrict__ resid,
    void* __restrict__ Cp, int M, int Nn, int K, const int* __restrict__ flag)
{
    constexpr int MT = (TN == 128) ? 4 : 2;
    __shared__ short As[128 * 64];
    __shared__ short Bs[TN * 64];
    int tid = threadIdx.x;
    int m0 = blockIdx.y * 128, n0 = blockIdx.x * TN;
    int lane = tid & 63, w = tid >> 6;
    int a_base = (TN == 128) ? (w >> 1) * 64 : w * 32;
    int b_base = (TN == 128) ? (w & 1) * 64 : 0;
    int mm = lane & 15, q = lane >> 4;

    f32x4 zero = {0.f, 0.f, 0.f, 0.f};
    f32x4 acc[MT][4];
    #pragma unroll
    for (int mt = 0; mt < MT; ++mt)
        #pragma unroll
        for (int nt = 0; nt < 4; ++nt) acc[mt][nt] = zero;

    int grow   = lane >> 3;
    int gchunk = ((lane & 7) ^ grow) * 8;
    const unsigned short* Ab = A  + (size_t)(m0 + w * 32 + grow) * K + gchunk;
    const unsigned short* Bb = Bt + (size_t)(n0 + w * (TN / 4) + grow) * K + gchunk;
    int swz = (mm & 7);

    for (int k0 = 0; k0 < K; k0 += 64) {
        __syncthreads();
        #pragma unroll
        for (int s = 0; s < 4; ++s)
            __builtin_amdgcn_global_load_lds(AS1(Ab + k0 + (size_t)(s * 8) * K),
                                             AS3(&As[(w * 32 + s * 8) * 64]), 16, 0, 0);
        #pragma unroll
        for (int s = 0; s < TN / 32; ++s)
            __builtin_amdgcn_global_load_lds(AS1(Bb + k0 + (size_t)(s * 8) * K),
                                             AS3(&Bs[(w * (TN / 4) + s * 8) * 64]), 16, 0, 0);
        __syncthreads();
        #pragma unroll
        for (int kk = 0; kk < 2; ++kk) {
            int col = ((kk * 4 + q) ^ swz) * 8;
            s8v af[MT], bf[4];
            #pragma unroll
            for (int mt = 0; mt < MT; ++mt)
                af[mt] = *(const s8v*)&As[(a_base + mt * 16 + mm) * 64 + col];
            #pragma unroll
            for (int nt = 0; nt < 4; ++nt)
                bf[nt] = *(const s8v*)&Bs[(b_base + nt * 16 + mm) * 64 + col];
            #pragma unroll
            for (int mt = 0; mt < MT; ++mt)
                #pragma unroll
                for (int nt = 0; nt < 4; ++nt)
                    acc[mt][nt] = __builtin_amdgcn_mfma_f32_16x16x32_bf16(
                        af[mt], bf[nt], acc[mt][nt], 0, 0, 0);
        }
    }

    int f = ODYN ? *flag : 1;
    #pragma unroll
    for (int nt = 0; nt < 4; ++nt) {
        int gc = n0 + b_base + nt * 16 + mm;
        float bv = bias ? b2f(bias[gc]) : 0.f;
        #pragma unroll
        for (int mt = 0; mt < MT; ++mt) {
            #pragma unroll
            for (int r = 0; r < 4; ++r) {
                int gr = m0 + a_base + mt * 16 + q * 4 + r;
                float v = acc[mt][nt][r] + bv;
                if (ACT == 1) v = gelu_f(v);
                if (RES == 1) v += b2f(resid[(size_t)gr * Nn + gc]);
                if (f) ((unsigned short*)Cp)[(size_t)gr * Nn + gc] = f2b(v);
                else   ((float*)Cp)[(size_t)gr * Nn + gc] = v;
            }
        }
    }
}

// ---------- flash attention v9: round-6 base (proven 49.5us) + MFMA-pipe l ----------
// Scores s = q.k/8 with LN'd inputs: |s| <~ 6, exp overflow-safe.
// Q pre-scaled by 0.125*log2(e) once; softmax = v_exp_f32 (2^x) directly.
// l computed via one extra mfma(P, ones) per PV step: removes 32 VALU adds per
// lane-stage AND the epilogue shuffle-reduce; l is self-consistent with the
// exact bf16 P used for O (absmax improves). Separate Ps buffer, 2 barriers per
// stage, launch_bounds (256,3) — tighter bounds proved to spill (r2/r9).
// Block = (b,h) x 64 queries, 4 waves; 128-key stages.
__global__ __launch_bounds__(256, 3) void fattn_k(
    const unsigned short* __restrict__ qkv, unsigned short* __restrict__ attn_out)
{
    int bh = blockIdx.x;
    int h = bh & (NHEAD - 1), b = bh >> 4;
    int qt = gridDim.y - 1 - blockIdx.y;          // heaviest first
    int q0 = qt * 64;
    size_t base = (size_t)b * NSEQ * (3 * D_MODEL);

    __shared__ __align__(16) short Ks[128][72];    // [key][dim]
    __shared__ __align__(16) short Vts[64][136];   // [dim][key pair-swizzled]
    __shared__ __align__(16) short Ps[64][136];    // [query][key, col+16*rowquad swizzle]

    int tid = threadIdx.x, lane = tid & 63, w = tid >> 6;
    int mm = lane & 15, q = lane >> 4;

    s8v qf[2];
    #pragma unroll
    for (int kk = 0; kk < 2; ++kk) {
        s8v v = *(const s8v*)(qkv + base + (size_t)(q0 + w * 16 + mm) * (3 * D_MODEL)
                              + h * HSZ + kk * 32 + q * 8);
        #pragma unroll
        for (int e = 0; e < 8; ++e) {   // fold 1/8 and log2(e) into Q once
            float f = b2f((unsigned short)v[e]) * 0.18033688011112042f;
            v[e] = (short)f2b(f);
        }
        qf[kk] = v;
    }

    s8v ones;                            // constant bf16 1.0 B-fragment for l-MFMA
    #pragma unroll
    for (int e = 0; e < 8; ++e) ones[e] = (short)0x3F80;

    f32x4 zero = {0.f, 0.f, 0.f, 0.f};
    f32x4 acc_o[4] = {zero, zero, zero, zero};
    f32x4 acc_l = zero;                  // l on the MFMA pipe

    int kr = tid >> 1;            // K staging row 0..127
    int kc = (tid & 1) * 32;      // 0 or 32
    int kp = tid >> 3;            // V key-pair 0..31
    int vd = (tid & 7) * 8;       // V dim base

    const unsigned short* kbase = qkv + base + D_MODEL + h * HSZ;
    const unsigned short* vbase = qkv + base + 2 * D_MODEL + h * HSZ;

    int nstages = (qt + 2) >> 1;

    // prologue: load stage 0 into registers
    s8v kv0, kv1, kv2, kv3, vv0, vv1, vv2, vv3;
    {
        const unsigned short* kb = kbase;
        const unsigned short* vb = vbase;
        kv0 = *(const s8v*)(kb + (size_t)kr * (3 * D_MODEL) + kc);
        kv1 = *(const s8v*)(kb + (size_t)kr * (3 * D_MODEL) + kc + 8);
        kv2 = *(const s8v*)(kb + (size_t)kr * (3 * D_MODEL) + kc + 16);
        kv3 = *(const s8v*)(kb + (size_t)kr * (3 * D_MODEL) + kc + 24);
        vv0 = *(const s8v*)(vb + (size_t)(2 * kp)      * (3 * D_MODEL) + vd);
        vv1 = *(const s8v*)(vb + (size_t)(2 * kp + 1)  * (3 * D_MODEL) + vd);
        vv2 = *(const s8v*)(vb + (size_t)(2 * kp + 64) * (3 * D_MODEL) + vd);
        vv3 = *(const s8v*)(vb + (size_t)(2 * kp + 65) * (3 * D_MODEL) + vd);
    }

    for (int t = 0; t < nstages; ++t) {
        int j0 = t * 128;
        int nsub = (j0 < q0) ? 2 : 1;

        __syncthreads();   // previous stage's LDS readers done
        *(s8v*)&Ks[kr][kc]      = kv0;
        *(s8v*)&Ks[kr][kc + 8]  = kv1;
        *(s8v*)&Ks[kr][kc + 16] = kv2;
        *(s8v*)&Ks[kr][kc + 24] = kv3;
        int c0 = (2 * kp + vd) & 63;
        #pragma unroll
        for (int e = 0; e < 8; ++e) {
            unsigned p0 = (unsigned)(unsigned short)vv0[e] |
                          ((unsigned)(unsigned short)vv1[e] << 16);
            unsigned p1 = (unsigned)(unsigned short)vv2[e] |
                          ((unsigned)(unsigned short)vv3[e] << 16);
            *(unsigned*)&Vts[vd + e][c0]      = p0;
            *(unsigned*)&Vts[vd + e][64 + c0] = p1;
        }
        // prefetch stage t+1 into registers (latency hidden behind compute)
        if (t + 1 < nstages) {
            const unsigned short* kb = kbase + (size_t)(j0 + 128) * (3 * D_MODEL);
            const unsigned short* vb = vbase + (size_t)(j0 + 128) * (3 * D_MODEL);
            kv0 = *(const s8v*)(kb + (size_t)kr * (3 * D_MODEL) + kc);
            kv1 = *(const s8v*)(kb + (size_t)kr * (3 * D_MODEL) + kc + 8);
            kv2 = *(const s8v*)(kb + (size_t)kr * (3 * D_MODEL) + kc + 16);
            kv3 = *(const s8v*)(kb + (size_t)kr * (3 * D_MODEL) + kc + 24);
            vv0 = *(const s8v*)(vb + (size_t)(2 * kp)      * (3 * D_MODEL) + vd);
            vv1 = *(const s8v*)(vb + (size_t)(2 * kp + 1)  * (3 * D_MODEL) + vd);
            vv2 = *(const s8v*)(vb + (size_t)(2 * kp + 64) * (3 * D_MODEL) + vd);
            vv3 = *(const s8v*)(vb + (size_t)(2 * kp + 65) * (3 * D_MODEL) + vd);
        }
        __syncthreads();   // LDS tile ready

        // S = Q K^T over up to 128 keys
        f32x4 sc[8];
        #pragma unroll
        for (int i = 0; i < 8; ++i) sc[i] = zero;
        __builtin_amdgcn_s_setprio(1);
        #pragma unroll
        for (int sub = 0; sub < 2; ++sub) {
            if (sub >= nsub) break;
            #pragma unroll
            for (int kk = 0; kk < 2; ++kk) {
                #pragma unroll
                for (int nt = 0; nt < 4; ++nt) {
                    s8v bv = *(const s8v*)&Ks[sub * 64 + nt * 16 + mm][kk * 32 + q * 8];
                    sc[sub * 4 + nt] = __builtin_amdgcn_mfma_f32_16x16x32_bf16(
                        qf[kk], bv, sc[sub * 4 + nt], 0, 0, 0);
                }
            }
        }
        __builtin_amdgcn_s_setprio(0);

        // p = exp2(s') (s' already includes 1/8*log2e); zero masked; pack P
        int pswz = 16 * q;   // writer row-quad swizzle
        #pragma unroll
        for (int sub = 0; sub < 2; ++sub) {
            if (sub >= nsub) break;
            bool need_mask = (j0 + sub * 64 + 63) > (q0 + w * 16);
            #pragma unroll
            for (int nt = 0; nt < 4; ++nt) {
                int gj = j0 + sub * 64 + nt * 16 + mm;
                #pragma unroll
                for (int r = 0; r < 4; ++r) {
                    float p = __builtin_amdgcn_exp2f(sc[sub * 4 + nt][r]);
                    if (need_mask && gj > (q0 + w * 16 + q * 4 + r)) p = 0.f;
                    Ps[w * 16 + q * 4 + r][sub * 64 + ((nt * 16 + mm + pswz) & 63)] =
                        (short)f2b_trunc(p);
                }
            }
        }
        // no barrier: each wave reads only its own P rows; Vts/Ks were barriered above

        // O += P V ; l += P . ones  (l on the MFMA pipe)
        int rq16 = 16 * ((mm >> 2) & 3);   // reader row-quad swizzle
        __builtin_amdgcn_s_setprio(1);
        #pragma unroll
        for (int kk4 = 0; kk4 < 4; ++kk4) {
            if (kk4 >= nsub * 2) break;
            int sub = kk4 >> 1, kkl = kk4 & 1;
            s8v av = *(const s8v*)&Ps[w * 16 + mm]
                        [sub * 64 + ((kkl * 32 + q * 8 + rq16) & 63)];
            #pragma unroll
            for (int nt = 0; nt < 4; ++nt) {
                int d = nt * 16 + mm;
                int c = sub * 64 + ((kkl * 32 + q * 8 + (d & 56)) & 63);
                s8v bv = *(const s8v*)&Vts[d][c];
                acc_o[nt] = __builtin_amdgcn_mfma_f32_16x16x32_bf16(av, bv, acc_o[nt], 0, 0, 0);
            }
            acc_l = __builtin_amdgcn_mfma_f32_16x16x32_bf16(av, ones, acc_l, 0, 0, 0);
        }
        __builtin_amdgcn_s_setprio(0);
    }

    // acc_l[r] already holds the full row sum (every output col identical)
    #pragma unroll
    for (int nt = 0; nt < 4; ++nt) {
        int d = nt * 16 + mm;
        #pragma unroll
        for (int r = 0; r < 4; ++r) {
            int row = q0 + w * 16 + q * 4 + r;
            attn_out[(size_t)(b * NSEQ + row) * D_MODEL + h * HSZ + d] =
                f2b(acc_o[nt][r] / acc_l[r]);
        }
    }
}

// ---------- launch ----------
extern "C" void kernel_launch(void* const* d_in, const int* in_sizes, int n_in,
                              void* d_out, int out_size, void* d_ws, size_t ws_size,
                              hipStream_t stream)
{
    const void* x_raw  = d_in[0];
    const void* ln1s_r = d_in[1];
    const void* ln1b_r = d_in[2];
    const void* wqkv_r = d_in[3];
    const void* wout_r = d_in[4];
    const void* bout_r = d_in[5];
    const void* ln2s_r = d_in[6];
    const void* ln2b_r = d_in[7];
    const void* w1_r   = d_in[8];
    const void* b1_r   = d_in[9];
    const void* w2_r   = d_in[10];
    const void* b2_r   = d_in[11];

    char* ws = (char*)d_ws;
    const size_t MB = 1024 * 1024;
    unsigned short* wt_qkv = (unsigned short*)(ws + 0 * MB);
    unsigned short* wt_out = (unsigned short*)(ws + 6 * MB);
    unsigned short* wt_w1  = (unsigned short*)(ws + 8 * MB);
    unsigned short* wt_w2  = (unsigned short*)(ws + 12 * MB);
    unsigned short* xb     = (unsigned short*)(ws + 16 * MB);
    unsigned short* xn     = (unsigned short*)(ws + 24 * MB);
    unsigned short* qkvb   = (unsigned short*)(ws + 32 * MB);
    unsigned short* x1     = (unsigned short*)(ws + 48 * MB);
    int*            flag   = (int*)           (ws + 56 * MB);
    unsigned short* cbias  = (unsigned short*)(ws + 56 * MB + 1024);
    unsigned short* attnb  = xn;
    unsigned short* xn2    = xn;
    unsigned short* hb     = qkvb;

    unsigned short* c_ln1s = cbias + 0;
    unsigned short* c_ln1b = cbias + 1024;
    unsigned short* c_bout = cbias + 2048;
    unsigned short* c_ln2s = cbias + 3072;
    unsigned short* c_ln2b = cbias + 4096;
    unsigned short* c_b1   = cbias + 5120;
    unsigned short* c_b2   = cbias + 7168;

    sniff_k<<<1, 256, 0, stream>>>((const unsigned short*)x_raw, flag);
    cvt_small_k<<<32, 256, 0, stream>>>(ln1s_r, ln1b_r, bout_r, ln2s_r, ln2b_r,
                                        b1_r, b2_r, cbias, flag);
    transpose_all_k<<<8192, 256, 0, stream>>>(wqkv_r, wout_r, w1_r, w2_r,
                                              wt_qkv, wt_out, wt_w1, wt_w2, flag);
    ln1f_k<<<MROWS, 256, 0, stream>>>(x_raw, c_ln1s, c_ln1b, xb, xn, flag);
    gemm128_k<128, 0, 0, 0><<<dim3(24, 32), 256, 0, stream>>>(
        xn, wt_qkv, nullptr, nullptr, qkvb, MROWS, 3072, 1024, flag);
    fattn_k<<<dim3(NBATCH * NHEAD, NSEQ / 64), 256, 0, stream>>>(qkvb, attnb);
    gemm128_k<64, 0, 1, 0><<<dim3(16, 32), 256, 0, stream>>>(
        attnb, wt_out, c_bout, xb, x1, MROWS, 1024, 1024, flag);
    ln_k<<<MROWS, 256, 0, stream>>>(x1, c_ln2s, c_ln2b, xn2);
    gemm128_k<128, 1, 0, 0><<<dim3(16, 32), 256, 0, stream>>>(
        xn2, wt_w1, c_b1, nullptr, hb, MROWS, 2048, 1024, flag);
    gemm128_k<64, 0, 1, 1><<<dim3(16, 32), 256, 0, stream>>>(
        hb, wt_w2, c_b2, x1, d_out, MROWS, 1024, 2048, flag);
}